// Round 12
// baseline (512.534 us; speedup 1.0000x reference)
//
#include <hip/hip_runtime.h>
#include <hip/hip_bf16.h>
#include <hip/hip_cooperative_groups.h>

namespace cg = cooperative_groups;

// Problem constants
static constexpr int NB = 16;     // batches
static constexpr int NP = 2048;   // points per batch
static constexpr int NC = 128;    // channels
#define ALPHA_F ((float)(8.0/9.0))
#define OMA_F   ((float)(1.0 - 8.0/9.0))

typedef __attribute__((ext_vector_type(8))) short bfrag;   // 8 bf16 (4 VGPR)
typedef __attribute__((ext_vector_type(4))) float ffrag;   // 4 fp32 acc

union BU { bfrag v; uint4 u; unsigned int w[4]; };

__device__ inline void split2(float x, float y, unsigned& hi, unsigned& lo) {
    __hip_bfloat162 h = __float22bfloat162_rn(make_float2(x, y));
    float2 hb = __bfloat1622float2(h);
    __hip_bfloat162 l = __float22bfloat162_rn(make_float2(x - hb.x, y - hb.y));
    __builtin_memcpy(&hi, &h, 4);
    __builtin_memcpy(&lo, &l, 4);
}

__device__ inline void split1(float x, unsigned short& h, unsigned short& l) {
    __hip_bfloat16 hb = __float2bfloat16(x);
    float hf = __bfloat162float(hb);
    __hip_bfloat16 lb = __float2bfloat16(x - hf);
    __builtin_memcpy(&h, &hb, 2);
    __builtin_memcpy(&l, &lb, 2);
}

// reconstruct 2 floats from packed hi/lo bf16 pair words
__device__ inline float2 pair2f(unsigned hu, unsigned lu) {
    unsigned hx = (hu & 0xFFFFu) << 16, hy = hu & 0xFFFF0000u;
    unsigned lx = (lu & 0xFFFFu) << 16, ly = lu & 0xFFFF0000u;
    float fhx, fhy, flx, fly;
    __builtin_memcpy(&fhx, &hx, 4); __builtin_memcpy(&fhy, &hy, 4);
    __builtin_memcpy(&flx, &lx, 4); __builtin_memcpy(&fly, &ly, 4);
    return make_float2(fhx + flx, fhy + fly);
}

// ---------------------------------------------------------------------------
// KNN v7.1 (unchanged: measured best, ~35us).
// ---------------------------------------------------------------------------
__global__ __launch_bounds__(256) void knn_kernel(const float* __restrict__ xyz,
                                                  int* __restrict__ nbr) {
    __shared__ float4 sp[NP];            // 32 KB (XOR-swizzled slots)
    __shared__ float  md[64][33];
    __shared__ int    mi[64][33];
    int b = blockIdx.y;
    const float* X = xyz + (size_t)b * 3 * NP;
    for (int m = threadIdx.x; m < NP; m += 256) {
        float x = X[m], y = X[NP + m], z = X[2 * NP + m];
        sp[m ^ ((m >> 5) & 7)] = make_float4(x, y, z, x * x + y * y + z * z);
    }
    __syncthreads();

    int tid = threadIdx.x;
    int p = tid >> 2;
    int q = tid & 3;
    int base = blockIdx.x * 64;
    int n = base + p;
    float4 me = sp[n ^ ((n >> 5) & 7)];
    float xi = me.x, yi = me.y, zi = me.z, qi = me.w;

    unsigned gd[8];
#pragma unroll
    for (int t = 0; t < 8; ++t) gd[t] = 0x7F7FFFFFu;
#pragma unroll 1
    for (int gg = 0; gg < 16; ++gg) {
        int g = q * 16 + gg;
        const float4* gp = sp + g * 32;
        float m0 = 3.4e38f, m1 = m0, m2 = m0, m3 = m0;
#pragma unroll
        for (int k = 0; k < 32; k += 4) {
            float4 a0 = gp[(k + 0) ^ q];
            float4 a1 = gp[(k + 1) ^ q];
            float4 a2 = gp[(k + 2) ^ q];
            float4 a3 = gp[(k + 3) ^ q];
            m0 = fminf(m0, qi + a0.w - 2.0f * (xi * a0.x + yi * a0.y + zi * a0.z));
            m1 = fminf(m1, qi + a1.w - 2.0f * (xi * a1.x + yi * a1.y + zi * a1.z));
            m2 = fminf(m2, qi + a2.w - 2.0f * (xi * a2.x + yi * a2.y + zi * a2.z));
            m3 = fminf(m3, qi + a3.w - 2.0f * (xi * a3.x + yi * a3.y + zi * a3.z));
        }
        float gm = fmaxf(fminf(fminf(m0, m1), fminf(m2, m3)), 0.0f);
        unsigned pg; __builtin_memcpy(&pg, &gm, 4);
        pg = (pg & ~63u) | (unsigned)g;
        unsigned prev = gd[0];
        gd[0] = gd[0] < pg ? gd[0] : pg;
#pragma unroll
        for (int t = 1; t < 8; ++t) {
            unsigned mx = prev > pg ? prev : pg;
            prev = gd[t];
            gd[t] = gd[t] < mx ? gd[t] : mx;
        }
    }

#define CEU(A, B) { unsigned _lo = (A) < (B) ? (A) : (B); \
                    unsigned _hi = (A) < (B) ? (B) : (A); (A) = _lo; (B) = _hi; }
    unsigned cA[8];
#pragma unroll
    for (int i = 0; i < 8; ++i) {
        unsigned pb = (unsigned)__shfl_xor((int)gd[7 - i], 1);
        cA[i] = gd[i] < pb ? gd[i] : pb;
    }
    CEU(cA[0], cA[4]); CEU(cA[1], cA[5]); CEU(cA[2], cA[6]); CEU(cA[3], cA[7]);
    CEU(cA[0], cA[2]); CEU(cA[1], cA[3]); CEU(cA[4], cA[6]); CEU(cA[5], cA[7]);
    CEU(cA[0], cA[1]); CEU(cA[2], cA[3]); CEU(cA[4], cA[5]); CEU(cA[6], cA[7]);
    unsigned dA[8];
#pragma unroll
    for (int i = 0; i < 8; ++i) {
        unsigned pb = (unsigned)__shfl_xor((int)cA[7 - i], 2);
        dA[i] = cA[i] < pb ? cA[i] : pb;
    }
    unsigned long long mask = 0ull;
#pragma unroll
    for (int i = 0; i < 8; ++i) mask |= (1ull << (dA[i] & 63u));

    float bd[8]; int bi[8];
#pragma unroll
    for (int t = 0; t < 8; ++t) { bd[t] = 3.4e38f; bi[t] = 0; }
    while (mask) {
        int g = (int)__builtin_ctzll(mask);
        mask &= (mask - 1ull);
        int sw = g & 7;
        int jb = g * 32 + q;
#pragma unroll
        for (int i = 0; i < 8; ++i) {
            int j0 = jb + i * 4;
            float4 c4v = sp[j0 ^ sw];
            float inner = xi * c4v.x + yi * c4v.y + zi * c4v.z;
            float d = qi + c4v.w - 2.0f * inner;
            bool c[8];
#pragma unroll
            for (int t = 0; t < 8; ++t) c[t] = d < bd[t];
#pragma unroll
            for (int t = 7; t >= 1; --t) {
                bd[t] = c[t - 1] ? bd[t - 1] : (c[t] ? d : bd[t]);
                bi[t] = c[t - 1] ? bi[t - 1] : (c[t] ? j0 : bi[t]);
            }
            bd[0] = c[0] ? d : bd[0];
            bi[0] = c[0] ? j0 : bi[0];
        }
    }
#pragma unroll
    for (int t = 0; t < 8; ++t) {
        md[p][q * 8 + t] = bd[t];
        mi[p][q * 8 + t] = bi[t];
    }
    __syncthreads();

    if (tid < 64) {
        float fd[8]; int fi[8];
#pragma unroll
        for (int t = 0; t < 8; ++t) { fd[t] = 3.4e38f; fi[t] = 0; }
#pragma unroll 4
        for (int cc = 0; cc < 32; ++cc) {
            float d = md[tid][cc];
            int j = mi[tid][cc];
            bool c[8];
#pragma unroll
            for (int t = 0; t < 8; ++t) c[t] = d < fd[t];
#pragma unroll
            for (int t = 7; t >= 1; --t) {
                fd[t] = c[t - 1] ? fd[t - 1] : (c[t] ? d : fd[t]);
                fi[t] = c[t - 1] ? fi[t - 1] : (c[t] ? j : fi[t]);
            }
            fd[0] = c[0] ? d : fd[0];
            fi[0] = c[0] ? j : fi[0];
        }
        int row = b * NP + base + tid;
#pragma unroll
        for (int t = 0; t < 7; ++t) nbr[row * 7 + t] = fi[t + 1];
    }
}

// ---------------------------------------------------------------------------
// Pre-split W into MFMA-frag-ordered bf16 hi/lo uint4 pairs (one-time).
// ---------------------------------------------------------------------------
__global__ __launch_bounds__(256) void prep_w_kernel(const float* __restrict__ Wc,
                                                     const float* __restrict__ Wg,
                                                     uint4* __restrict__ WP) {
    int t = blockIdx.x * 256 + threadIdx.x;
    int ncol = t & 127;
    int quad = (t >> 7) & 3;
    int s = (t >> 9) & 3;
    int mat = (t >> 11) & 1;
    int layer = t >> 12;
    const float* W = (mat ? Wg : Wc) + (size_t)layer * NC * NC + (size_t)ncol * NC + s * 32 + quad * 8;
    float4 a = *((const float4*)W);
    float4 b = *((const float4*)(W + 4));
    BU hi, lo;
    split2(a.x, a.y, hi.w[0], lo.w[0]);
    split2(a.z, a.w, hi.w[1], lo.w[1]);
    split2(b.x, b.y, hi.w[2], lo.w[2]);
    split2(b.z, b.w, hi.w[3], lo.w[3]);
    WP[t * 2] = hi.u;
    WP[t * 2 + 1] = lo.u;
}

// ---------------------------------------------------------------------------
// MFMA + epilogue for one GCN layer (persistent kernel). Z is written BACK
// into the hi/lo planes (no separate Zl): epilogue reads p = hi+lo at its
// exclusive (row,col), computes Z = p + alpha*accC, writes split(Z) back.
// __syncthreads separates plane-wide MFMA reads from the overwrite.
// ---------------------------------------------------------------------------
__device__ __forceinline__ void mfma_layer(const uint4* __restrict__ WPc,
                                           const uint4* __restrict__ WPg,
                                           unsigned short (&AhT)[64][136],
                                           unsigned short (&AlT)[64][136],
                                           float* __restrict__ yout,
                                           size_t m0, int quad, int l15, int ncol) {
    BU Bch[4], Bcl[4], Bgh[4], Bgl[4];
#pragma unroll
    for (int s = 0; s < 4; ++s) {
        int idx = ((s * 4 + quad) * 128 + ncol) * 2;
        Bch[s].u = WPc[idx];
        Bcl[s].u = WPc[idx + 1];
        Bgh[s].u = WPg[idx];
        Bgl[s].u = WPg[idx + 1];
    }
    ffrag accC[4], accG[4];
#pragma unroll
    for (int mt = 0; mt < 4; ++mt) { accC[mt] = (ffrag)0.0f; accG[mt] = (ffrag)0.0f; }
#pragma unroll
    for (int s = 0; s < 4; ++s) {
#pragma unroll
        for (int mt = 0; mt < 4; ++mt) {
            int m = mt * 16 + l15;
            int k = s * 32 + quad * 8;
            BU ah, al, rh, rl;
            ah.u = *((const uint4*)&AhT[m][k]);
            al.u = *((const uint4*)&AlT[m][k]);
#pragma unroll
            for (int w = 0; w < 4; ++w) {
                unsigned msk = ((ah.w[w] & 0x80008000u) >> 15) * 0xFFFFu;
                rh.w[w] = ah.w[w] & ~msk;
                rl.w[w] = al.w[w] & ~msk;
            }
            accC[mt] = __builtin_amdgcn_mfma_f32_16x16x32_bf16(rh.v, Bch[s].v, accC[mt], 0, 0, 0);
            accC[mt] = __builtin_amdgcn_mfma_f32_16x16x32_bf16(rh.v, Bcl[s].v, accC[mt], 0, 0, 0);
            accC[mt] = __builtin_amdgcn_mfma_f32_16x16x32_bf16(rl.v, Bch[s].v, accC[mt], 0, 0, 0);
            accG[mt] = __builtin_amdgcn_mfma_f32_16x16x32_bf16(ah.v, Bgh[s].v, accG[mt], 0, 0, 0);
            accG[mt] = __builtin_amdgcn_mfma_f32_16x16x32_bf16(ah.v, Bgl[s].v, accG[mt], 0, 0, 0);
            accG[mt] = __builtin_amdgcn_mfma_f32_16x16x32_bf16(al.v, Bgh[s].v, accG[mt], 0, 0, 0);
        }
    }
    __syncthreads();   // all MFMA plane reads done before plane overwrite
#pragma unroll
    for (int mt = 0; mt < 4; ++mt) {
        int rbase = mt * 16 + quad * 4;
#pragma unroll
        for (int r = 0; r < 4; ++r) {
            int rr = rbase + r;
            unsigned hb = ((unsigned)AhT[rr][ncol]) << 16;
            unsigned lb = ((unsigned)AlT[rr][ncol]) << 16;
            float hp, lp;
            __builtin_memcpy(&hp, &hb, 4);
            __builtin_memcpy(&lp, &lb, 4);
            float z = (hp + lp) + ALPHA_F * accC[mt][r];
            unsigned short zh, zl;
            split1(z, zh, zl);
            AhT[rr][ncol] = zh;
            AlT[rr][ncol] = zl;
            yout[(m0 + rr) * NC + ncol] = accG[mt][r];
        }
    }
}

// ---------------------------------------------------------------------------
// Persistent cooperative GCN (round-12, slim): LDS 41.8 KB (2 blocks/CU with
// margin; was 76.5 KB -> coop launch rejected). Z lives in the bf16 hi/lo
// planes across layers; only Y2 round-trips global with grid.sync().
// ---------------------------------------------------------------------------
__global__ __launch_bounds__(512, 4) void gcn_persistent_kernel(
        const float* __restrict__ points,
        const int* __restrict__ nbr,
        const uint4* __restrict__ WP,
        const float* __restrict__ Wuc,
        const float* __restrict__ Wug,
        const float* __restrict__ xyz,
        float* __restrict__ Ya,
        float* __restrict__ Yb,
        float* __restrict__ U,
        float* __restrict__ out) {
    cg::grid_group grid = cg::this_grid();

    __shared__ unsigned short AhT[64][136];   // 17.4 KB
    __shared__ unsigned short AlT[64][136];   // 17.4 KB
    __shared__ int   s_nb[448];               // 1.8 KB
    __shared__ float sW[12 * NC];             // 6 KB

    int tid = threadIdx.x;
    int wid = tid >> 6, lane = tid & 63;
    int quad = lane >> 4, l15 = lane & 15;
    int xcd = blockIdx.x & 7;
    int slot = blockIdx.x >> 3;
    int bb = xcd * 2 + (slot >> 5);
    int n0 = (slot & 31) << 6;
    size_t m0 = (size_t)bb * NP + n0;
    size_t bbase = (size_t)bb * NP;
    int ncol = wid * 16 + l15;

    if (tid < 448) s_nb[tid] = nbr[m0 * 7 + tid];
    for (int m = tid; m < 12 * NC; m += 512)
        sW[m] = (m < 6 * NC) ? Wuc[m] : Wug[m - 6 * NC];

    // ---- layer 0: stage A from points (B,C,N)
#pragma unroll
    for (int it = 0; it < 4; ++it) {
        int f = tid + it * 512;
        int c = f >> 4, rq = (f & 15) * 4;
        float4 v = *((const float4*)(points + ((size_t)bb * NC + c) * NP + n0 + rq));
        float vv[4] = {v.x, v.y, v.z, v.w};
#pragma unroll
        for (int k = 0; k < 4; ++k) {
            unsigned short h, l;
            split1(vv[k], h, l);
            AhT[rq + k][c] = h;
            AlT[rq + k][c] = l;
        }
    }
    __syncthreads();
    mfma_layer(WP, WP + 4096, AhT, AlT, Ya, m0, quad, l15, ncol);
    grid.sync();

    // ---- layers 1..3: z from planes, Y2 gathered from global
#pragma unroll 1
    for (int L = 1; L < 4; ++L) {
        const float* yin  = (L & 1) ? Ya : Yb;
        float*       yout = (L & 1) ? Yb : Ya;
        const uint4* WPc = WP + (size_t)(L * 2 + 0) * 4096;
        const uint4* WPg = WP + (size_t)(L * 2 + 1) * 4096;

#pragma unroll 1
        for (int it = 0; it < 4; ++it) {
            int f = tid + it * 512;
            int r = f >> 5, c4 = (f & 31) * 4;
            size_t row = m0 + r;
            float4 acc = *((const float4*)(yin + row * NC + c4));
#pragma unroll
            for (int t = 0; t < 7; ++t) {
                int j = s_nb[r * 7 + t];
                float4 v = *((const float4*)(yin + (bbase + (size_t)j) * NC + c4));
                acc.x += v.x; acc.y += v.y; acc.z += v.z; acc.w += v.w;
            }
            uint2 hu = *((const uint2*)&AhT[r][c4]);
            uint2 lu = *((const uint2*)&AlT[r][c4]);
            float2 z01 = pair2f(hu.x, lu.x);
            float2 z23 = pair2f(hu.y, lu.y);
            float4 a;
            a.x = OMA_F * (0.125f * acc.x) + z01.x;
            a.y = OMA_F * (0.125f * acc.y) + z01.y;
            a.z = OMA_F * (0.125f * acc.z) + z23.x;
            a.w = OMA_F * (0.125f * acc.w) + z23.y;
            unsigned h01, l01, h23, l23;
            split2(a.x, a.y, h01, l01);
            split2(a.z, a.w, h23, l23);
            *((uint2*)&AhT[r][c4]) = make_uint2(h01, h23);
            *((uint2*)&AlT[r][c4]) = make_uint2(l01, l23);
        }
        __syncthreads();
        mfma_layer(WPc, WPg, AhT, AlT, yout, m0, quad, l15, ncol);
        grid.sync();
    }

    // ---- tail A: P = OMA*(0.125*(Yb own+nbrs)) + z, written back to planes
#pragma unroll 1
    for (int it = 0; it < 4; ++it) {
        int f = tid + it * 512;
        int r = f >> 5, c4 = (f & 31) * 4;
        size_t row = m0 + r;
        float4 ys = *((const float4*)(Yb + row * NC + c4));
#pragma unroll
        for (int t = 0; t < 7; ++t) {
            int j = s_nb[r * 7 + t];
            float4 v = *((const float4*)(Yb + (bbase + (size_t)j) * NC + c4));
            ys.x += v.x; ys.y += v.y; ys.z += v.z; ys.w += v.w;
        }
        uint2 hu = *((const uint2*)&AhT[r][c4]);
        uint2 lu = *((const uint2*)&AlT[r][c4]);
        float2 z01 = pair2f(hu.x, lu.x);
        float2 z23 = pair2f(hu.y, lu.y);
        float4 o;
        o.x = OMA_F * (0.125f * ys.x) + z01.x;
        o.y = OMA_F * (0.125f * ys.y) + z01.y;
        o.z = OMA_F * (0.125f * ys.z) + z23.x;
        o.w = OMA_F * (0.125f * ys.w) + z23.y;
        unsigned h01, l01, h23, l23;
        split2(o.x, o.y, h01, l01);
        split2(o.z, o.w, h23, l23);
        *((uint2*)&AhT[r][c4]) = make_uint2(h01, h23);
        *((uint2*)&AlT[r][c4]) = make_uint2(l01, l23);
    }
    __syncthreads();

    // ---- tail B: U = [P@Wuc^T | P@Wug^T], 8 lanes/row, shfl tree
    {
        int row = tid >> 3, k = tid & 7;
        float a1[6] = {0, 0, 0, 0, 0, 0}, a2[6] = {0, 0, 0, 0, 0, 0};
#pragma unroll
        for (int i = 0; i < 4; ++i) {
            int c4 = k * 16 + i * 4;
            uint2 hu = *((const uint2*)&AhT[row][c4]);
            uint2 lu = *((const uint2*)&AlT[row][c4]);
            float2 p01 = pair2f(hu.x, lu.x);
            float2 p23 = pair2f(hu.y, lu.y);
#pragma unroll
            for (int oo = 0; oo < 6; ++oo) {
                float4 w1 = *((const float4*)&sW[oo * NC + c4]);
                float4 w2 = *((const float4*)&sW[(6 + oo) * NC + c4]);
                a1[oo] += p01.x * w1.x + p01.y * w1.y + p23.x * w1.z + p23.y * w1.w;
                a2[oo] += p01.x * w2.x + p01.y * w2.y + p23.x * w2.z + p23.y * w2.w;
            }
        }
#pragma unroll
        for (int s = 1; s < 8; s <<= 1) {
#pragma unroll
            for (int oo = 0; oo < 6; ++oo) {
                a1[oo] += __shfl_xor(a1[oo], s);
                a2[oo] += __shfl_xor(a2[oo], s);
            }
        }
        if (k == 0) {
            float* Ur = U + (m0 + row) * 12;
            *((float4*)(Ur + 0)) = make_float4(a1[0], a1[1], a1[2], a1[3]);
            *((float4*)(Ur + 4)) = make_float4(a1[4], a1[5], a2[0], a2[1]);
            *((float4*)(Ur + 8)) = make_float4(a2[2], a2[3], a2[4], a2[5]);
        }
    }

    // ---- tail C: transpose P tile -> out2 (B,C,N)
    {
        float* out2 = out + (size_t)NB * 3 * 2 * NP;
#pragma unroll
        for (int it = 0; it < 4; ++it) {
            int u = tid + it * 512;
            int c = u >> 4, nseg = (u & 15) * 4;
            float4 v;
#pragma unroll
            for (int j = 0; j < 4; ++j) {
                unsigned hb = ((unsigned)AhT[nseg + j][c]) << 16;
                unsigned lb = ((unsigned)AlT[nseg + j][c]) << 16;
                float hp, lp;
                __builtin_memcpy(&hp, &hb, 4);
                __builtin_memcpy(&lp, &lb, 4);
                ((float*)&v)[j] = hp + lp;
            }
            *((float4*)(out2 + ((size_t)bb * NC + c) * NP + n0 + nseg)) = v;
        }
    }
    grid.sync();

    // ---- tail D: new_xyz (needs all tiles' U)
    if (tid < 64) {
        size_t row = m0 + tid;
        int n = n0 + tid;
        const int* nb = s_nb + tid * 7;
        float u1[6], u2[6];
#pragma unroll
        for (int o = 0; o < 6; ++o) { u1[o] = U[row * 12 + o]; u2[o] = U[row * 12 + 6 + o]; }
#pragma unroll
        for (int t = 0; t < 7; ++t) {
            int j = nb[t];
            const float* Uj = U + (bbase + (size_t)j) * 12 + 6;
#pragma unroll
            for (int o = 0; o < 6; ++o) u2[o] += Uj[o];
        }
#pragma unroll
        for (int c = 0; c < 3; ++c)
#pragma unroll
            for (int s = 0; s < 2; ++s) {
                int o = c * 2 + s;
                float val = ALPHA_F * u1[o] + OMA_F * (0.125f * u2[o])
                          + xyz[(size_t)bb * 3 * NP + (size_t)c * NP + n];
                out[(size_t)bb * 3 * 2 * NP + (size_t)c * 2 * NP + (size_t)s * NP + n] = val;
            }
    }
}

// ===========================================================================
// Fallback path (v11, measured 197.3us): separate launches.
// ===========================================================================
template <int MODE>
__global__ __launch_bounds__(512, 4) void gemm_fused_kernel(const float* __restrict__ Asrc,
                                                            const float* __restrict__ Y2in,
                                                            const int* __restrict__ nbr,
                                                            const uint4* __restrict__ WPc,
                                                            const uint4* __restrict__ WPg,
                                                            float* __restrict__ Zout,
                                                            float* __restrict__ Y2out) {
    __shared__ unsigned short AhT[64][136];
    __shared__ unsigned short AlT[64][136];
    __shared__ int s_nb[448];
    int tid = threadIdx.x;
    int wid = tid >> 6, lane = tid & 63;
    int quad = lane >> 4, l15 = lane & 15;
    int xcd = blockIdx.x & 7;
    int slot = blockIdx.x >> 3;
    int bb = xcd * 2 + (slot >> 5);
    int n0 = (slot & 31) << 6;
    size_t m0 = (size_t)bb * NP + n0;
    int ncol = wid * 16 + l15;

    if (MODE == 1) {
        if (tid < 448) s_nb[tid] = nbr[m0 * 7 + tid];
        __syncthreads();
        size_t bbase = (size_t)bb * NP;
#pragma unroll 1
        for (int it = 0; it < 4; ++it) {
            int f = tid + it * 512;
            int r = f >> 5, c4 = (f & 31) * 4;
            size_t row = m0 + r;
            float4 z = *((const float4*)(Asrc + row * NC + c4));
            float4 acc = *((const float4*)(Y2in + row * NC + c4));
#pragma unroll
            for (int t = 0; t < 7; ++t) {
                int j = s_nb[r * 7 + t];
                float4 v = *((const float4*)(Y2in + (bbase + (size_t)j) * NC + c4));
                acc.x += v.x; acc.y += v.y; acc.z += v.z; acc.w += v.w;
            }
            float4 a;
            a.x = OMA_F * (0.125f * acc.x) + z.x;
            a.y = OMA_F * (0.125f * acc.y) + z.y;
            a.z = OMA_F * (0.125f * acc.z) + z.z;
            a.w = OMA_F * (0.125f * acc.w) + z.w;
            unsigned h01, l01, h23, l23;
            split2(a.x, a.y, h01, l01);
            split2(a.z, a.w, h23, l23);
            *((uint2*)&AhT[r][c4]) = make_uint2(h01, h23);
            *((uint2*)&AlT[r][c4]) = make_uint2(l01, l23);
        }
    } else {
#pragma unroll
        for (int it = 0; it < 4; ++it) {
            int f = tid + it * 512;
            int c = f >> 4, rq = (f & 15) * 4;
            float4 v = *((const float4*)(Asrc + ((size_t)bb * NC + c) * NP + n0 + rq));
            float vv[4] = {v.x, v.y, v.z, v.w};
#pragma unroll
            for (int k = 0; k < 4; ++k) {
                unsigned short h, l;
                split1(vv[k], h, l);
                AhT[rq + k][c] = h;
                AlT[rq + k][c] = l;
            }
        }
    }
    __syncthreads();

    BU Bch[4], Bcl[4], Bgh[4], Bgl[4];
#pragma unroll
    for (int s = 0; s < 4; ++s) {
        int idx = ((s * 4 + quad) * 128 + ncol) * 2;
        Bch[s].u = WPc[idx];
        Bcl[s].u = WPc[idx + 1];
        Bgh[s].u = WPg[idx];
        Bgl[s].u = WPg[idx + 1];
    }

    ffrag accC[4], accG[4];
#pragma unroll
    for (int mt = 0; mt < 4; ++mt) { accC[mt] = (ffrag)0.0f; accG[mt] = (ffrag)0.0f; }

#pragma unroll
    for (int s = 0; s < 4; ++s) {
#pragma unroll
        for (int mt = 0; mt < 4; ++mt) {
            int m = mt * 16 + l15;
            int k = s * 32 + quad * 8;
            BU ah, al, rh, rl;
            ah.u = *((const uint4*)&AhT[m][k]);
            al.u = *((const uint4*)&AlT[m][k]);
#pragma unroll
            for (int w = 0; w < 4; ++w) {
                unsigned msk = ((ah.w[w] & 0x80008000u) >> 15) * 0xFFFFu;
                rh.w[w] = ah.w[w] & ~msk;
                rl.w[w] = al.w[w] & ~msk;
            }
            accC[mt] = __builtin_amdgcn_mfma_f32_16x16x32_bf16(rh.v, Bch[s].v, accC[mt], 0, 0, 0);
            accC[mt] = __builtin_amdgcn_mfma_f32_16x16x32_bf16(rh.v, Bcl[s].v, accC[mt], 0, 0, 0);
            accC[mt] = __builtin_amdgcn_mfma_f32_16x16x32_bf16(rl.v, Bch[s].v, accC[mt], 0, 0, 0);
            accG[mt] = __builtin_amdgcn_mfma_f32_16x16x32_bf16(ah.v, Bgh[s].v, accG[mt], 0, 0, 0);
            accG[mt] = __builtin_amdgcn_mfma_f32_16x16x32_bf16(ah.v, Bgl[s].v, accG[mt], 0, 0, 0);
            accG[mt] = __builtin_amdgcn_mfma_f32_16x16x32_bf16(al.v, Bgh[s].v, accG[mt], 0, 0, 0);
        }
    }

#pragma unroll
    for (int mt = 0; mt < 4; ++mt) {
        int rbase = mt * 16 + quad * 4;
#pragma unroll
        for (int r = 0; r < 4; ++r) {
            int rr = rbase + r;
            unsigned hb = ((unsigned)AhT[rr][ncol]) << 16;
            unsigned lb = ((unsigned)AlT[rr][ncol]) << 16;
            float hp, lp;
            __builtin_memcpy(&hp, &hb, 4);
            __builtin_memcpy(&lp, &lb, 4);
            float p = hp + lp;
            size_t idx = (m0 + rr) * NC + ncol;
            Zout[idx] = p + ALPHA_F * accC[mt][r];
            Y2out[idx] = accG[mt][r];
        }
    }
}

__global__ __launch_bounds__(256) void agg2_kernel(const float* __restrict__ Z,
                                                   const float* __restrict__ Y2,
                                                   const int* __restrict__ nbr,
                                                   const float* __restrict__ Wuc,
                                                   const float* __restrict__ Wug,
                                                   float* __restrict__ U,
                                                   float* __restrict__ out2) {
    __shared__ float s1[6 * NC], s2[6 * NC];
    __shared__ float sm[8][132];
    int tid = threadIdx.x;
    int lane = tid & 31, rl = tid >> 5;
    for (int m = tid; m < 6 * NC; m += 256) { s1[m] = Wuc[m]; s2[m] = Wug[m]; }

    int xcd = blockIdx.x & 7;
    int slot = blockIdx.x >> 3;
    int bb = xcd * 2 + (slot >> 8);
    int rblk = slot & 255;
    int n0 = rblk * 8;
    size_t row = ((size_t)bb << 11) + n0 + rl;
    const int* nb = nbr + row * 7;
    size_t off = row * NC + lane * 4;
    float4 ys = *((const float4*)(Y2 + off));
    size_t bbase = (size_t)bb * NP * NC;
#pragma unroll
    for (int t = 0; t < 7; ++t) {
        int j = nb[t];
        float4 v = *((const float4*)(Y2 + bbase + (size_t)j * NC + lane * 4));
        ys.x += v.x; ys.y += v.y; ys.z += v.z; ys.w += v.w;
    }
    float4 z = *((const float4*)(Z + off));
    float4 o;
    o.x = OMA_F * (0.125f * ys.x) + z.x;
    o.y = OMA_F * (0.125f * ys.y) + z.y;
    o.z = OMA_F * (0.125f * ys.z) + z.z;
    o.w = OMA_F * (0.125f * ys.w) + z.w;

    __syncthreads();
    *((float4*)&sm[rl][lane * 4]) = o;

    float a1[6], a2[6];
#pragma unroll
    for (int oo = 0; oo < 6; ++oo) {
        float4 w1 = *((const float4*)&s1[oo * NC + lane * 4]);
        float4 w2 = *((const float4*)&s2[oo * NC + lane * 4]);
        a1[oo] = o.x * w1.x + o.y * w1.y + o.z * w1.z + o.w * w1.w;
        a2[oo] = o.x * w2.x + o.y * w2.y + o.z * w2.z + o.w * w2.w;
    }
#pragma unroll
    for (int s = 1; s < 32; s <<= 1) {
#pragma unroll
        for (int oo = 0; oo < 6; ++oo) {
            a1[oo] += __shfl_xor(a1[oo], s);
            a2[oo] += __shfl_xor(a2[oo], s);
        }
    }
    if (lane == 0) {
        float* Ur = U + row * 12;
        *((float4*)(Ur + 0)) = make_float4(a1[0], a1[1], a1[2], a1[3]);
        *((float4*)(Ur + 4)) = make_float4(a1[4], a1[5], a2[0], a2[1]);
        *((float4*)(Ur + 8)) = make_float4(a2[2], a2[3], a2[4], a2[5]);
    }

    __syncthreads();
    int c = tid >> 1, h = tid & 1;
    float4 v;
    v.x = sm[4 * h + 0][c];
    v.y = sm[4 * h + 1][c];
    v.z = sm[4 * h + 2][c];
    v.w = sm[4 * h + 3][c];
    *((float4*)(out2 + ((size_t)bb * NC + c) * NP + n0 + 4 * h)) = v;
}

__global__ __launch_bounds__(256) void final_out_kernel(const float* __restrict__ U,
                                                        const int* __restrict__ nbr,
                                                        const float* __restrict__ xyz,
                                                        float* __restrict__ out) {
    size_t row = (size_t)blockIdx.x * 256 + threadIdx.x;
    int b = (int)(row >> 11), n = (int)(row & 2047);
    const int* nb = nbr + row * 7;
    float u1[6], u2[6];
#pragma unroll
    for (int o = 0; o < 6; ++o) { u1[o] = U[row * 12 + o]; u2[o] = U[row * 12 + 6 + o]; }
#pragma unroll
    for (int t = 0; t < 7; ++t) {
        int j = nb[t];
        const float* Uj = U + ((size_t)b * NP + j) * 12 + 6;
#pragma unroll
        for (int o = 0; o < 6; ++o) u2[o] += Uj[o];
    }
#pragma unroll
    for (int c = 0; c < 3; ++c)
#pragma unroll
        for (int s = 0; s < 2; ++s) {
            int o = c * 2 + s;
            float val = ALPHA_F * u1[o] + OMA_F * (0.125f * u2[o])
                      + xyz[(size_t)b * 3 * NP + (size_t)c * NP + n];
            out[(size_t)b * 3 * 2 * NP + (size_t)c * 2 * NP + (size_t)s * NP + n] = val;
        }
}

// ---------------------------------------------------------------------------
extern "C" void kernel_launch(void* const* d_in, const int* in_sizes, int n_in,
                              void* d_out, int out_size, void* d_ws, size_t ws_size,
                              hipStream_t stream) {
    const float* xyz    = (const float*)d_in[0];
    const float* points = (const float*)d_in[1];
    const float* Wc     = (const float*)d_in[2];
    const float* Wg     = (const float*)d_in[3];
    const float* Wuc    = (const float*)d_in[4];
    const float* Wug    = (const float*)d_in[5];
    float* out = (float*)d_out;

    char* ws = (char*)d_ws;
    size_t o = 0;
    int* nbr  = (int*)(ws + o);     o += (size_t)NB * NP * 7 * 4;
    uint4* WP = (uint4*)(ws + o);   o += (size_t)32768 * 16;
    float* Za = (float*)(ws + o);   o += (size_t)NB * NP * NC * 4;
    float* Ya = (float*)(ws + o);   o += (size_t)NB * NP * NC * 4;
    float* Zb = (float*)(ws + o);   o += (size_t)NB * NP * NC * 4;
    float* Yb = (float*)(ws + o);   o += (size_t)NB * NP * NC * 4;
    float* U  = (float*)(ws + o);   o += (size_t)NB * NP * 12 * 4;

    const int GEMM_GRID = NB * NP / 64;
    #define WPC(L) (WP + (size_t)((L) * 2 + 0) * 4096)
    #define WPG(L) (WP + (size_t)((L) * 2 + 1) * 4096)

    prep_w_kernel<<<64, 256, 0, stream>>>(Wc, Wg, WP);
    knn_kernel<<<dim3(NP / 64, NB), 256, 0, stream>>>(xyz, nbr);

    // Try the persistent cooperative path; fall back to v11 on rejection.
    void* args[] = {(void*)&points, (void*)&nbr, (void*)&WP, (void*)&Wuc,
                    (void*)&Wug, (void*)&xyz, (void*)&Ya, (void*)&Yb,
                    (void*)&U, (void*)&out};
    hipError_t e = hipLaunchCooperativeKernel((void*)gcn_persistent_kernel,
                                              dim3(512), dim3(512), args, 0, stream);
    if (e != hipSuccess) {
        float* out2 = out + (size_t)NB * 3 * 2 * NP;
        gemm_fused_kernel<0><<<GEMM_GRID, 512, 0, stream>>>(points, nullptr, nullptr,
            WPC(0), WPG(0), Za, Ya);
        gemm_fused_kernel<1><<<GEMM_GRID, 512, 0, stream>>>(Za, Ya, nbr,
            WPC(1), WPG(1), Zb, Yb);
        gemm_fused_kernel<1><<<GEMM_GRID, 512, 0, stream>>>(Zb, Yb, nbr,
            WPC(2), WPG(2), Za, Ya);
        gemm_fused_kernel<1><<<GEMM_GRID, 512, 0, stream>>>(Za, Ya, nbr,
            WPC(3), WPG(3), Zb, Yb);
        agg2_kernel<<<dim3(NB * NP / 8), 256, 0, stream>>>(Zb, Yb, nbr, Wuc, Wug, U, out2);
        final_out_kernel<<<dim3(NB * NP / 256), 256, 0, stream>>>(U, nbr, xyz, out);
    }
}

// Round 15
// 198.628 us; speedup vs baseline: 2.5804x; 2.5804x over previous
//
#include <hip/hip_runtime.h>
#include <hip/hip_bf16.h>

// Problem constants
static constexpr int NB = 16;     // batches
static constexpr int NP = 2048;   // points per batch
static constexpr int NC = 128;    // channels
#define ALPHA_F ((float)(8.0/9.0))
#define OMA_F   ((float)(1.0 - 8.0/9.0))

typedef __attribute__((ext_vector_type(8))) short bfrag;   // 8 bf16 (4 VGPR)
typedef __attribute__((ext_vector_type(4))) float ffrag;   // 4 fp32 acc

union BU { bfrag v; uint4 u; unsigned int w[4]; };

__device__ inline void split2(float x, float y, unsigned& hi, unsigned& lo) {
    __hip_bfloat162 h = __float22bfloat162_rn(make_float2(x, y));
    float2 hb = __bfloat1622float2(h);
    __hip_bfloat162 l = __float22bfloat162_rn(make_float2(x - hb.x, y - hb.y));
    __builtin_memcpy(&hi, &h, 4);
    __builtin_memcpy(&lo, &l, 4);
}

__device__ inline void split1(float x, unsigned short& h, unsigned short& l) {
    __hip_bfloat16 hb = __float2bfloat16(x);
    float hf = __bfloat162float(hb);
    __hip_bfloat16 lb = __float2bfloat16(x - hf);
    __builtin_memcpy(&h, &hb, 2);
    __builtin_memcpy(&l, &lb, 2);
}

// ---------------------------------------------------------------------------
// KNN v10 (round-15 resubmit; rounds 13/14 were infra failures, untested).
// v7.1 per-lane program, 128 queries/block.
// Geometry: 512 threads = 128 queries x 4 lanes, grid (NP/128, NB) = 256
// blocks -> staging paid once per 128 queries (per-CU: S+2C vs v7's 2S+2C).
// Per-lane program byte-identical to v7.1 (16 owned groups, min/max
// sorted-insert, 2-stage bitonic merge, 8-group pass-2). md/mi[128][33]
// overlaid on sp after a barrier (v8-proven pattern). LDS 33.8 KB.
// ---------------------------------------------------------------------------
__global__ __launch_bounds__(512) void knn_kernel(const float* __restrict__ xyz,
                                                  int* __restrict__ nbr) {
    __shared__ __align__(16) char shraw[33792];        // max(32768 sp, 2*128*33*4)
    float4* sp = (float4*)shraw;                       // 2048 slots (swizzled)
    float (*md)[33] = (float(*)[33])shraw;             // overlay after pass 2
    int   (*mi)[33] = (int(*)[33])(shraw + 128 * 33 * 4);

    int tid = threadIdx.x;
    int b = blockIdx.y;
    const float* X = xyz + (size_t)b * 3 * NP;
    for (int m = tid; m < NP; m += 512) {
        float x = X[m], y = X[NP + m], z = X[2 * NP + m];
        sp[m ^ ((m >> 5) & 7)] = make_float4(x, y, z, x * x + y * y + z * z);
    }
    __syncthreads();

    int p = tid >> 2;          // query within tile (0..127)
    int q = tid & 3;           // lane within query
    int base = blockIdx.x * 128;
    int n = base + p;
    float4 me = sp[n ^ ((n >> 5) & 7)];
    float xi = me.x, yi = me.y, zi = me.z, qi = me.w;

    // ---- pass 1: true group-min for the 16 owned groups (g = q*16 + gg)
    unsigned gd[8];
#pragma unroll
    for (int t = 0; t < 8; ++t) gd[t] = 0x7F7FFFFFu;
#pragma unroll 1
    for (int gg = 0; gg < 16; ++gg) {
        int g = q * 16 + gg;
        const float4* gp = sp + g * 32;
        float m0 = 3.4e38f, m1 = m0, m2 = m0, m3 = m0;
#pragma unroll
        for (int k = 0; k < 32; k += 4) {
            float4 a0 = gp[(k + 0) ^ q];
            float4 a1 = gp[(k + 1) ^ q];
            float4 a2 = gp[(k + 2) ^ q];
            float4 a3 = gp[(k + 3) ^ q];
            m0 = fminf(m0, qi + a0.w - 2.0f * (xi * a0.x + yi * a0.y + zi * a0.z));
            m1 = fminf(m1, qi + a1.w - 2.0f * (xi * a1.x + yi * a1.y + zi * a1.z));
            m2 = fminf(m2, qi + a2.w - 2.0f * (xi * a2.x + yi * a2.y + zi * a2.z));
            m3 = fminf(m3, qi + a3.w - 2.0f * (xi * a3.x + yi * a3.y + zi * a3.z));
        }
        float gm = fmaxf(fminf(fminf(m0, m1), fminf(m2, m3)), 0.0f);
        unsigned pg; __builtin_memcpy(&pg, &gm, 4);
        pg = (pg & ~63u) | (unsigned)g;
        unsigned prev = gd[0];
        gd[0] = gd[0] < pg ? gd[0] : pg;
#pragma unroll
        for (int t = 1; t < 8; ++t) {
            unsigned mx = prev > pg ? prev : pg;
            prev = gd[t];
            gd[t] = gd[t] < mx ? gd[t] : mx;
        }
    }

    // ---- cross-lane merge: top-8 of the 4 lanes' sorted 8-lists (bitonic)
#define CEU(A, B) { unsigned _lo = (A) < (B) ? (A) : (B); \
                    unsigned _hi = (A) < (B) ? (B) : (A); (A) = _lo; (B) = _hi; }
    unsigned cA[8];
#pragma unroll
    for (int i = 0; i < 8; ++i) {
        unsigned pb = (unsigned)__shfl_xor((int)gd[7 - i], 1);
        cA[i] = gd[i] < pb ? gd[i] : pb;
    }
    CEU(cA[0], cA[4]); CEU(cA[1], cA[5]); CEU(cA[2], cA[6]); CEU(cA[3], cA[7]);
    CEU(cA[0], cA[2]); CEU(cA[1], cA[3]); CEU(cA[4], cA[6]); CEU(cA[5], cA[7]);
    CEU(cA[0], cA[1]); CEU(cA[2], cA[3]); CEU(cA[4], cA[5]); CEU(cA[6], cA[7]);
    unsigned dA[8];
#pragma unroll
    for (int i = 0; i < 8; ++i) {
        unsigned pb = (unsigned)__shfl_xor((int)cA[7 - i], 2);
        dA[i] = cA[i] < pb ? cA[i] : pb;
    }
    unsigned long long mask = 0ull;
#pragma unroll
    for (int i = 0; i < 8; ++i) mask |= (1ull << (dA[i] & 63u));

    // ---- pass 2: full insert over winning groups, ascending group order
    float bd[8]; int bi[8];
#pragma unroll
    for (int t = 0; t < 8; ++t) { bd[t] = 3.4e38f; bi[t] = 0; }
    while (mask) {
        int g = (int)__builtin_ctzll(mask);
        mask &= (mask - 1ull);
        int sw = g & 7;
        int jb = g * 32 + q;
#pragma unroll
        for (int i = 0; i < 8; ++i) {
            int j0 = jb + i * 4;
            float4 c4v = sp[j0 ^ sw];
            float inner = xi * c4v.x + yi * c4v.y + zi * c4v.z;
            float d = qi + c4v.w - 2.0f * inner;
            bool c[8];
#pragma unroll
            for (int t = 0; t < 8; ++t) c[t] = d < bd[t];
#pragma unroll
            for (int t = 7; t >= 1; --t) {
                bd[t] = c[t - 1] ? bd[t - 1] : (c[t] ? d : bd[t]);
                bi[t] = c[t - 1] ? bi[t - 1] : (c[t] ? j0 : bi[t]);
            }
            bd[0] = c[0] ? d : bd[0];
            bi[0] = c[0] ? j0 : bi[0];
        }
    }
    __syncthreads();            // sp dead; overlay md/mi
#pragma unroll
    for (int t = 0; t < 8; ++t) {
        md[p][q * 8 + t] = bd[t];
        mi[p][q * 8 + t] = bi[t];
    }
    __syncthreads();

    if (tid < 128) {
        float fd[8]; int fi[8];
#pragma unroll
        for (int t = 0; t < 8; ++t) { fd[t] = 3.4e38f; fi[t] = 0; }
#pragma unroll 4
        for (int cc = 0; cc < 32; ++cc) {
            float d = md[tid][cc];
            int j = mi[tid][cc];
            bool c[8];
#pragma unroll
            for (int t = 0; t < 8; ++t) c[t] = d < fd[t];
#pragma unroll
            for (int t = 7; t >= 1; --t) {
                fd[t] = c[t - 1] ? fd[t - 1] : (c[t] ? d : fd[t]);
                fi[t] = c[t - 1] ? fi[t - 1] : (c[t] ? j : fi[t]);
            }
            fd[0] = c[0] ? d : fd[0];
            fi[0] = c[0] ? j : fi[0];
        }
        int row = b * NP + base + tid;
#pragma unroll
        for (int t = 0; t < 7; ++t) nbr[row * 7 + t] = fi[t + 1];
    }
}

// ---------------------------------------------------------------------------
// Pre-split W into MFMA-frag-ordered bf16 hi/lo uint4 pairs (one-time).
// ---------------------------------------------------------------------------
__global__ __launch_bounds__(256) void prep_w_kernel(const float* __restrict__ Wc,
                                                     const float* __restrict__ Wg,
                                                     uint4* __restrict__ WP) {
    int t = blockIdx.x * 256 + threadIdx.x;
    int ncol = t & 127;
    int quad = (t >> 7) & 3;
    int s = (t >> 9) & 3;
    int mat = (t >> 11) & 1;
    int layer = t >> 12;
    const float* W = (mat ? Wg : Wc) + (size_t)layer * NC * NC + (size_t)ncol * NC + s * 32 + quad * 8;
    float4 a = *((const float4*)W);
    float4 b = *((const float4*)(W + 4));
    BU hi, lo;
    split2(a.x, a.y, hi.w[0], lo.w[0]);
    split2(a.z, a.w, hi.w[1], lo.w[1]);
    split2(b.x, b.y, hi.w[2], lo.w[2]);
    split2(b.z, b.w, hi.w[3], lo.w[3]);
    WP[t * 2] = hi.u;
    WP[t * 2 + 1] = lo.u;
}

// ---------------------------------------------------------------------------
// Fused GCN block v6 (round-15 resubmit): occupancy 16 -> 24 waves/CU.
// Round-12's persistent kernel measured VGPR_Count=64 (+32 acc AGPR) for the
// same MFMA structure -> unified pressure ~96 -> 4 waves/SIMD -> 2 blocks/CU,
// though LDS (35.75 KB) allows 3+. Fix: __launch_bounds__(512, 6) (cap ~85
// unified regs) + B-frags loaded INSIDE the `#pragma unroll 1` K-step loop
// (one 16-VGPR B-set live instead of 64; WP is L2-hot, reload ~free).
// Live set ~ acc 32 + B 16 + A 32 + addr ~ 80 < 85 -> no spills,
// 3 blocks/CU. Layers are memory-latency bound; +50% waves in flight.
// Math identical.
// ---------------------------------------------------------------------------
template <int MODE>
__global__ __launch_bounds__(512, 6) void gemm_fused_kernel(const float* __restrict__ Asrc,
                                                            const float* __restrict__ Y2in,
                                                            const int* __restrict__ nbr,
                                                            const uint4* __restrict__ WPc,
                                                            const uint4* __restrict__ WPg,
                                                            float* __restrict__ Zout,
                                                            float* __restrict__ Y2out) {
    __shared__ unsigned short AhT[64][136];   // 17.4 KB
    __shared__ unsigned short AlT[64][136];   // 17.4 KB
    __shared__ int s_nb[448];
    int tid = threadIdx.x;
    int wid = tid >> 6, lane = tid & 63;
    int quad = lane >> 4, l15 = lane & 15;
    int xcd = blockIdx.x & 7;
    int slot = blockIdx.x >> 3;
    int bb = xcd * 2 + (slot >> 5);           // batch
    int n0 = (slot & 31) << 6;                // tile base within batch
    size_t m0 = (size_t)bb * NP + n0;
    int ncol = wid * 16 + l15;

    // ---- stage A tile, splitting to bf16 planes inline
    if (MODE == 1) {
        if (tid < 448) s_nb[tid] = nbr[m0 * 7 + tid];
        __syncthreads();
        size_t bbase = (size_t)bb * NP;
#pragma unroll 1
        for (int it = 0; it < 4; ++it) {
            int f = tid + it * 512;
            int r = f >> 5, c4 = (f & 31) * 4;
            size_t row = m0 + r;
            float4 z = *((const float4*)(Asrc + row * NC + c4));
            float4 acc = *((const float4*)(Y2in + row * NC + c4));
#pragma unroll
            for (int t = 0; t < 7; ++t) {
                int j = s_nb[r * 7 + t];
                float4 v = *((const float4*)(Y2in + (bbase + (size_t)j) * NC + c4));
                acc.x += v.x; acc.y += v.y; acc.z += v.z; acc.w += v.w;
            }
            float4 a;
            a.x = OMA_F * (0.125f * acc.x) + z.x;
            a.y = OMA_F * (0.125f * acc.y) + z.y;
            a.z = OMA_F * (0.125f * acc.z) + z.z;
            a.w = OMA_F * (0.125f * acc.w) + z.w;
            unsigned h01, l01, h23, l23;
            split2(a.x, a.y, h01, l01);
            split2(a.z, a.w, h23, l23);
            *((uint2*)&AhT[r][c4]) = make_uint2(h01, h23);
            *((uint2*)&AlT[r][c4]) = make_uint2(l01, l23);
        }
    } else {
        // A[r][c] = points[b][c][n0+r]: float4 along n, split scalar, b16 writes
#pragma unroll
        for (int it = 0; it < 4; ++it) {
            int f = tid + it * 512;
            int c = f >> 4, rq = (f & 15) * 4;
            float4 v = *((const float4*)(Asrc + ((size_t)bb * NC + c) * NP + n0 + rq));
            float vv[4] = {v.x, v.y, v.z, v.w};
#pragma unroll
            for (int k = 0; k < 4; ++k) {
                unsigned short h, l;
                split1(vv[k], h, l);
                AhT[rq + k][c] = h;
                AlT[rq + k][c] = l;
            }
        }
    }
    __syncthreads();

    ffrag accC[4], accG[4];
#pragma unroll
    for (int mt = 0; mt < 4; ++mt) { accC[mt] = (ffrag)0.0f; accG[mt] = (ffrag)0.0f; }

    // K-step loop: B-frags loaded per-s (one set live), loop kept rolled so
    // the compiler cannot hoist all 4 sets (which would re-inflate pressure).
#pragma unroll 1
    for (int s = 0; s < 4; ++s) {
        BU Bch, Bcl, Bgh, Bgl;
        int idx = ((s * 4 + quad) * 128 + ncol) * 2;
        Bch.u = WPc[idx];
        Bcl.u = WPc[idx + 1];
        Bgh.u = WPg[idx];
        Bgl.u = WPg[idx + 1];
#pragma unroll
        for (int mt = 0; mt < 4; ++mt) {
            int m = mt * 16 + l15;
            int k = s * 32 + quad * 8;
            BU ah, al, rh, rl;
            ah.u = *((const uint4*)&AhT[m][k]);
            al.u = *((const uint4*)&AlT[m][k]);
#pragma unroll
            for (int w = 0; w < 4; ++w) {
                unsigned msk = ((ah.w[w] & 0x80008000u) >> 15) * 0xFFFFu;
                rh.w[w] = ah.w[w] & ~msk;
                rl.w[w] = al.w[w] & ~msk;
            }
            accC[mt] = __builtin_amdgcn_mfma_f32_16x16x32_bf16(rh.v, Bch.v, accC[mt], 0, 0, 0);
            accC[mt] = __builtin_amdgcn_mfma_f32_16x16x32_bf16(rh.v, Bcl.v, accC[mt], 0, 0, 0);
            accC[mt] = __builtin_amdgcn_mfma_f32_16x16x32_bf16(rl.v, Bch.v, accC[mt], 0, 0, 0);
            accG[mt] = __builtin_amdgcn_mfma_f32_16x16x32_bf16(ah.v, Bgh.v, accG[mt], 0, 0, 0);
            accG[mt] = __builtin_amdgcn_mfma_f32_16x16x32_bf16(ah.v, Bgl.v, accG[mt], 0, 0, 0);
            accG[mt] = __builtin_amdgcn_mfma_f32_16x16x32_bf16(al.v, Bgh.v, accG[mt], 0, 0, 0);
        }
    }

    // ---- epilogue: col = l15, row = 4*quad + r; residual p = hi + lo
#pragma unroll
    for (int mt = 0; mt < 4; ++mt) {
        int rbase = mt * 16 + quad * 4;
#pragma unroll
        for (int r = 0; r < 4; ++r) {
            int rr = rbase + r;
            unsigned hb = ((unsigned)AhT[rr][ncol]) << 16;
            unsigned lb = ((unsigned)AlT[rr][ncol]) << 16;
            float hp, lp;
            __builtin_memcpy(&hp, &hb, 4);
            __builtin_memcpy(&lp, &lb, 4);
            float p = hp + lp;
            size_t idx = (m0 + rr) * NC + ncol;
            Zout[idx] = p + ALPHA_F * accC[mt][r];
            Y2out[idx] = accG[mt][r];
        }
    }
}

// ---------------------------------------------------------------------------
// agg2 (unchanged from v11): fused tail = agg + final_gemm + transpose.
// ---------------------------------------------------------------------------
__global__ __launch_bounds__(256) void agg2_kernel(const float* __restrict__ Z,
                                                   const float* __restrict__ Y2,
                                                   const int* __restrict__ nbr,
                                                   const float* __restrict__ Wuc,
                                                   const float* __restrict__ Wug,
                                                   float* __restrict__ U,
                                                   float* __restrict__ out2) {
    __shared__ float s1[6 * NC], s2[6 * NC];
    __shared__ float sm[8][132];
    int tid = threadIdx.x;
    int lane = tid & 31, rl = tid >> 5;
    for (int m = tid; m < 6 * NC; m += 256) { s1[m] = Wuc[m]; s2[m] = Wug[m]; }

    int xcd = blockIdx.x & 7;
    int slot = blockIdx.x >> 3;
    int bb = xcd * 2 + (slot >> 8);
    int rblk = slot & 255;
    int n0 = rblk * 8;
    size_t row = ((size_t)bb << 11) + n0 + rl;
    const int* nb = nbr + row * 7;
    size_t off = row * NC + lane * 4;
    float4 ys = *((const float4*)(Y2 + off));
    size_t bbase = (size_t)bb * NP * NC;
#pragma unroll
    for (int t = 0; t < 7; ++t) {
        int j = nb[t];
        float4 v = *((const float4*)(Y2 + bbase + (size_t)j * NC + lane * 4));
        ys.x += v.x; ys.y += v.y; ys.z += v.z; ys.w += v.w;
    }
    float4 z = *((const float4*)(Z + off));
    float4 o;
    o.x = OMA_F * (0.125f * ys.x) + z.x;
    o.y = OMA_F * (0.125f * ys.y) + z.y;
    o.z = OMA_F * (0.125f * ys.z) + z.z;
    o.w = OMA_F * (0.125f * ys.w) + z.w;

    __syncthreads();
    *((float4*)&sm[rl][lane * 4]) = o;

    float a1[6], a2[6];
#pragma unroll
    for (int oo = 0; oo < 6; ++oo) {
        float4 w1 = *((const float4*)&s1[oo * NC + lane * 4]);
        float4 w2 = *((const float4*)&s2[oo * NC + lane * 4]);
        a1[oo] = o.x * w1.x + o.y * w1.y + o.z * w1.z + o.w * w1.w;
        a2[oo] = o.x * w2.x + o.y * w2.y + o.z * w2.z + o.w * w2.w;
    }
#pragma unroll
    for (int s = 1; s < 32; s <<= 1) {
#pragma unroll
        for (int oo = 0; oo < 6; ++oo) {
            a1[oo] += __shfl_xor(a1[oo], s);
            a2[oo] += __shfl_xor(a2[oo], s);
        }
    }
    if (lane == 0) {
        float* Ur = U + row * 12;
        *((float4*)(Ur + 0)) = make_float4(a1[0], a1[1], a1[2], a1[3]);
        *((float4*)(Ur + 4)) = make_float4(a1[4], a1[5], a2[0], a2[1]);
        *((float4*)(Ur + 8)) = make_float4(a2[2], a2[3], a2[4], a2[5]);
    }

    __syncthreads();
    int c = tid >> 1, h = tid & 1;
    float4 v;
    v.x = sm[4 * h + 0][c];
    v.y = sm[4 * h + 1][c];
    v.z = sm[4 * h + 2][c];
    v.w = sm[4 * h + 3][c];
    *((float4*)(out2 + ((size_t)bb * NC + c) * NP + n0 + 4 * h)) = v;
}

// ---------------------------------------------------------------------------
// Final output: new_xyz (unchanged from v11)
// ---------------------------------------------------------------------------
__global__ __launch_bounds__(256) void final_out_kernel(const float* __restrict__ U,
                                                        const int* __restrict__ nbr,
                                                        const float* __restrict__ xyz,
                                                        float* __restrict__ out) {
    size_t row = (size_t)blockIdx.x * 256 + threadIdx.x;
    int b = (int)(row >> 11), n = (int)(row & 2047);
    const int* nb = nbr + row * 7;
    float u1[6], u2[6];
#pragma unroll
    for (int o = 0; o < 6; ++o) { u1[o] = U[row * 12 + o]; u2[o] = U[row * 12 + 6 + o]; }
#pragma unroll
    for (int t = 0; t < 7; ++t) {
        int j = nb[t];
        const float* Uj = U + ((size_t)b * NP + j) * 12 + 6;
#pragma unroll
        for (int o = 0; o < 6; ++o) u2[o] += Uj[o];
    }
#pragma unroll
    for (int c = 0; c < 3; ++c)
#pragma unroll
        for (int s = 0; s < 2; ++s) {
            int o = c * 2 + s;
            float val = ALPHA_F * u1[o] + OMA_F * (0.125f * u2[o])
                      + xyz[(size_t)b * 3 * NP + (size_t)c * NP + n];
            out[(size_t)b * 3 * 2 * NP + (size_t)c * 2 * NP + (size_t)s * NP + n] = val;
        }
}

// ---------------------------------------------------------------------------
extern "C" void kernel_launch(void* const* d_in, const int* in_sizes, int n_in,
                              void* d_out, int out_size, void* d_ws, size_t ws_size,
                              hipStream_t stream) {
    const float* xyz    = (const float*)d_in[0];  // (16,3,2048)
    const float* points = (const float*)d_in[1];  // (16,128,2048)
    const float* Wc     = (const float*)d_in[2];  // (4,128,128)
    const float* Wg     = (const float*)d_in[3];  // (4,128,128)
    const float* Wuc    = (const float*)d_in[4];  // (6,128)
    const float* Wug    = (const float*)d_in[5];  // (6,128)
    float* out = (float*)d_out;

    char* ws = (char*)d_ws;
    size_t o = 0;
    int* nbr  = (int*)(ws + o);     o += (size_t)NB * NP * 7 * 4;
    uint4* WP = (uint4*)(ws + o);   o += (size_t)32768 * 16;           // 0.5 MB
    float* Za = (float*)(ws + o);   o += (size_t)NB * NP * NC * 4;     // 16 MB
    float* Ya = (float*)(ws + o);   o += (size_t)NB * NP * NC * 4;
    float* Zb = (float*)(ws + o);   o += (size_t)NB * NP * NC * 4;
    float* Yb = (float*)(ws + o);   o += (size_t)NB * NP * NC * 4;
    float* U  = (float*)(ws + o);   o += (size_t)NB * NP * 12 * 4;

    const int GEMM_GRID = NB * NP / 64;   // 512 tiles
    #define WPC(L) (WP + (size_t)((L) * 2 + 0) * 4096)
    #define WPG(L) (WP + (size_t)((L) * 2 + 1) * 4096)

    // 0) pre-split weights (one-time)
    prep_w_kernel<<<64, 256, 0, stream>>>(Wc, Wg, WP);
    // 1) KNN (128 queries/block x 4 lanes, 512 threads, 256 blocks)
    knn_kernel<<<dim3(NP / 128, NB), 512, 0, stream>>>(xyz, nbr);
    // 2) GCN blocks — agg fused into next block's A-staging
    gemm_fused_kernel<0><<<GEMM_GRID, 512, 0, stream>>>(points, nullptr, nullptr,
        WPC(0), WPG(0), Za, Ya);
    gemm_fused_kernel<1><<<GEMM_GRID, 512, 0, stream>>>(Za, Ya, nbr,
        WPC(1), WPG(1), Zb, Yb);
    gemm_fused_kernel<1><<<GEMM_GRID, 512, 0, stream>>>(Zb, Yb, nbr,
        WPC(2), WPG(2), Za, Ya);
    gemm_fused_kernel<1><<<GEMM_GRID, 512, 0, stream>>>(Za, Ya, nbr,
        WPC(3), WPG(3), Zb, Yb);
    // 3) fused tail: last agg + final small GEMMs + transpose
    float* out2 = out + (size_t)NB * 3 * 2 * NP;
    agg2_kernel<<<dim3(NB * NP / 8), 256, 0, stream>>>(Zb, Yb, nbr, Wuc, Wug, U, out2);
    // 4) new_xyz
    final_out_kernel<<<dim3(NB * NP / 256), 256, 0, stream>>>(U, nbr, xyz, out);
}

// Round 16
// 190.995 us; speedup vs baseline: 2.6835x; 1.0400x over previous
//
#include <hip/hip_runtime.h>
#include <hip/hip_bf16.h>

// Problem constants
static constexpr int NB = 16;     // batches
static constexpr int NP = 2048;   // points per batch
static constexpr int NC = 128;    // channels
#define ALPHA_F ((float)(8.0/9.0))
#define OMA_F   ((float)(1.0 - 8.0/9.0))

typedef __attribute__((ext_vector_type(8))) short bfrag;   // 8 bf16 (4 VGPR)
typedef __attribute__((ext_vector_type(4))) float ffrag;   // 4 fp32 acc

union BU { bfrag v; uint4 u; unsigned int w[4]; };

__device__ inline void split2(float x, float y, unsigned& hi, unsigned& lo) {
    __hip_bfloat162 h = __float22bfloat162_rn(make_float2(x, y));
    float2 hb = __bfloat1622float2(h);
    __hip_bfloat162 l = __float22bfloat162_rn(make_float2(x - hb.x, y - hb.y));
    __builtin_memcpy(&hi, &h, 4);
    __builtin_memcpy(&lo, &l, 4);
}

__device__ inline void split1(float x, unsigned short& h, unsigned short& l) {
    __hip_bfloat16 hb = __float2bfloat16(x);
    float hf = __bfloat162float(hb);
    __hip_bfloat16 lb = __float2bfloat16(x - hf);
    __builtin_memcpy(&h, &hb, 2);
    __builtin_memcpy(&l, &lb, 2);
}

// unpack 4 packed bf16 (uint2) -> float4
__device__ inline float4 bf16x4_to_f32x4(uint2 u) {
    unsigned w0 = (u.x & 0xFFFFu) << 16, w1 = u.x & 0xFFFF0000u;
    unsigned w2 = (u.y & 0xFFFFu) << 16, w3 = u.y & 0xFFFF0000u;
    float4 r;
    __builtin_memcpy(&r.x, &w0, 4);
    __builtin_memcpy(&r.y, &w1, 4);
    __builtin_memcpy(&r.z, &w2, 4);
    __builtin_memcpy(&r.w, &w3, 4);
    return r;
}

// pack float -> bf16 ushort (RNE)
__device__ inline unsigned short f32_to_bf16u(float x) {
    __hip_bfloat16 h = __float2bfloat16(x);
    unsigned short u;
    __builtin_memcpy(&u, &h, 2);
    return u;
}

// ---------------------------------------------------------------------------
// KNN v7.1 (reverted to measured best, ~35us).
// ---------------------------------------------------------------------------
__global__ __launch_bounds__(256) void knn_kernel(const float* __restrict__ xyz,
                                                  int* __restrict__ nbr) {
    __shared__ float4 sp[NP];            // 32 KB (XOR-swizzled slots)
    __shared__ float  md[64][33];
    __shared__ int    mi[64][33];
    int b = blockIdx.y;
    const float* X = xyz + (size_t)b * 3 * NP;
    for (int m = threadIdx.x; m < NP; m += 256) {
        float x = X[m], y = X[NP + m], z = X[2 * NP + m];
        sp[m ^ ((m >> 5) & 7)] = make_float4(x, y, z, x * x + y * y + z * z);
    }
    __syncthreads();

    int tid = threadIdx.x;
    int p = tid >> 2;
    int q = tid & 3;
    int base = blockIdx.x * 64;
    int n = base + p;
    float4 me = sp[n ^ ((n >> 5) & 7)];
    float xi = me.x, yi = me.y, zi = me.z, qi = me.w;

    // ---- pass 1: true group-min for the 16 owned groups (g = q*16 + gg)
    unsigned gd[8];
#pragma unroll
    for (int t = 0; t < 8; ++t) gd[t] = 0x7F7FFFFFu;
#pragma unroll 1
    for (int gg = 0; gg < 16; ++gg) {
        int g = q * 16 + gg;
        const float4* gp = sp + g * 32;
        float m0 = 3.4e38f, m1 = m0, m2 = m0, m3 = m0;
#pragma unroll
        for (int k = 0; k < 32; k += 4) {
            float4 a0 = gp[(k + 0) ^ q];
            float4 a1 = gp[(k + 1) ^ q];
            float4 a2 = gp[(k + 2) ^ q];
            float4 a3 = gp[(k + 3) ^ q];
            m0 = fminf(m0, qi + a0.w - 2.0f * (xi * a0.x + yi * a0.y + zi * a0.z));
            m1 = fminf(m1, qi + a1.w - 2.0f * (xi * a1.x + yi * a1.y + zi * a1.z));
            m2 = fminf(m2, qi + a2.w - 2.0f * (xi * a2.x + yi * a2.y + zi * a2.z));
            m3 = fminf(m3, qi + a3.w - 2.0f * (xi * a3.x + yi * a3.y + zi * a3.z));
        }
        float gm = fmaxf(fminf(fminf(m0, m1), fminf(m2, m3)), 0.0f);
        unsigned pg; __builtin_memcpy(&pg, &gm, 4);
        pg = (pg & ~63u) | (unsigned)g;
        // sorted-insert via min/max identity (keys unique -> exact)
        unsigned prev = gd[0];
        gd[0] = gd[0] < pg ? gd[0] : pg;
#pragma unroll
        for (int t = 1; t < 8; ++t) {
            unsigned mx = prev > pg ? prev : pg;
            prev = gd[t];
            gd[t] = gd[t] < mx ? gd[t] : mx;
        }
    }

    // ---- cross-lane merge: top-8 of the 4 lanes' sorted lists (bitonic)
#define CEU(A, B) { unsigned _lo = (A) < (B) ? (A) : (B); \
                    unsigned _hi = (A) < (B) ? (B) : (A); (A) = _lo; (B) = _hi; }
    unsigned cA[8];
#pragma unroll
    for (int i = 0; i < 8; ++i) {
        unsigned pb = (unsigned)__shfl_xor((int)gd[7 - i], 1);
        cA[i] = gd[i] < pb ? gd[i] : pb;
    }
    CEU(cA[0], cA[4]); CEU(cA[1], cA[5]); CEU(cA[2], cA[6]); CEU(cA[3], cA[7]);
    CEU(cA[0], cA[2]); CEU(cA[1], cA[3]); CEU(cA[4], cA[6]); CEU(cA[5], cA[7]);
    CEU(cA[0], cA[1]); CEU(cA[2], cA[3]); CEU(cA[4], cA[5]); CEU(cA[6], cA[7]);
    unsigned dA[8];
#pragma unroll
    for (int i = 0; i < 8; ++i) {
        unsigned pb = (unsigned)__shfl_xor((int)cA[7 - i], 2);
        dA[i] = cA[i] < pb ? cA[i] : pb;
    }
    unsigned long long mask = 0ull;
#pragma unroll
    for (int i = 0; i < 8; ++i) mask |= (1ull << (dA[i] & 63u));

    // ---- pass 2: full insert over winning groups, ascending group order
    float bd[8]; int bi[8];
#pragma unroll
    for (int t = 0; t < 8; ++t) { bd[t] = 3.4e38f; bi[t] = 0; }
    while (mask) {
        int g = (int)__builtin_ctzll(mask);
        mask &= (mask - 1ull);
        int sw = g & 7;
        int jb = g * 32 + q;
#pragma unroll
        for (int i = 0; i < 8; ++i) {
            int j0 = jb + i * 4;
            float4 c4v = sp[j0 ^ sw];
            float inner = xi * c4v.x + yi * c4v.y + zi * c4v.z;
            float d = qi + c4v.w - 2.0f * inner;
            bool c[8];
#pragma unroll
            for (int t = 0; t < 8; ++t) c[t] = d < bd[t];
#pragma unroll
            for (int t = 7; t >= 1; --t) {
                bd[t] = c[t - 1] ? bd[t - 1] : (c[t] ? d : bd[t]);
                bi[t] = c[t - 1] ? bi[t - 1] : (c[t] ? j0 : bi[t]);
            }
            bd[0] = c[0] ? d : bd[0];
            bi[0] = c[0] ? j0 : bi[0];
        }
    }
#pragma unroll
    for (int t = 0; t < 8; ++t) {
        md[p][q * 8 + t] = bd[t];
        mi[p][q * 8 + t] = bi[t];
    }
    __syncthreads();

    if (tid < 64) {
        float fd[8]; int fi[8];
#pragma unroll
        for (int t = 0; t < 8; ++t) { fd[t] = 3.4e38f; fi[t] = 0; }
#pragma unroll 4
        for (int cc = 0; cc < 32; ++cc) {
            float d = md[tid][cc];
            int j = mi[tid][cc];
            bool c[8];
#pragma unroll
            for (int t = 0; t < 8; ++t) c[t] = d < fd[t];
#pragma unroll
            for (int t = 7; t >= 1; --t) {
                fd[t] = c[t - 1] ? fd[t - 1] : (c[t] ? d : fd[t]);
                fi[t] = c[t - 1] ? fi[t - 1] : (c[t] ? j : fi[t]);
            }
            fd[0] = c[0] ? d : fd[0];
            fi[0] = c[0] ? j : fi[0];
        }
        int row = b * NP + base + tid;
#pragma unroll
        for (int t = 0; t < 7; ++t) nbr[row * 7 + t] = fi[t + 1];
    }
}

// ---------------------------------------------------------------------------
// Pre-split W into MFMA-frag-ordered bf16 hi/lo uint4 pairs (one-time).
// ---------------------------------------------------------------------------
__global__ __launch_bounds__(256) void prep_w_kernel(const float* __restrict__ Wc,
                                                     const float* __restrict__ Wg,
                                                     uint4* __restrict__ WP) {
    int t = blockIdx.x * 256 + threadIdx.x;
    int ncol = t & 127;
    int quad = (t >> 7) & 3;
    int s = (t >> 9) & 3;
    int mat = (t >> 11) & 1;
    int layer = t >> 12;
    const float* W = (mat ? Wg : Wc) + (size_t)layer * NC * NC + (size_t)ncol * NC + s * 32 + quad * 8;
    float4 a = *((const float4*)W);
    float4 b = *((const float4*)(W + 4));
    BU hi, lo;
    split2(a.x, a.y, hi.w[0], lo.w[0]);
    split2(a.z, a.w, hi.w[1], lo.w[1]);
    split2(b.x, b.y, hi.w[2], lo.w[2]);
    split2(b.z, b.w, hi.w[3], lo.w[3]);
    WP[t * 2] = hi.u;
    WP[t * 2 + 1] = lo.u;
}

// ---------------------------------------------------------------------------
// Fused GCN block v7 (round-16): v11 structure + bf16 Y2 storage.
// Y2 is the only tensor whose full 16 MB crosses every layer boundary AND is
// gathered 7x/row. bf16 halves its write+read traffic (~72 MB total) and
// drops the per-XCD gather working set 2->1 MB (solidly L2-resident),
// attacking the gather-latency term. Y2 enters pts only as OMA/8 * sum8
// (~1.4% weight), so bf16's 2^-9 rel error is negligible vs the 7x absmax
// headroom. Structure otherwise identical to v11 ((512,4), W-frags after
// barrier, unroll-1 staging).
// ---------------------------------------------------------------------------
template <int MODE>
__global__ __launch_bounds__(512, 4) void gemm_fused_kernel(const float* __restrict__ Asrc,
                                                            const unsigned short* __restrict__ Y2in,
                                                            const int* __restrict__ nbr,
                                                            const uint4* __restrict__ WPc,
                                                            const uint4* __restrict__ WPg,
                                                            float* __restrict__ Zout,
                                                            unsigned short* __restrict__ Y2out) {
    __shared__ unsigned short AhT[64][136];   // 17.4 KB
    __shared__ unsigned short AlT[64][136];   // 17.4 KB
    __shared__ int s_nb[448];
    int tid = threadIdx.x;
    int wid = tid >> 6, lane = tid & 63;
    int quad = lane >> 4, l15 = lane & 15;
    int xcd = blockIdx.x & 7;
    int slot = blockIdx.x >> 3;
    int bb = xcd * 2 + (slot >> 5);           // batch
    int n0 = (slot & 31) << 6;                // tile base within batch
    size_t m0 = (size_t)bb * NP + n0;
    int ncol = wid * 16 + l15;

    // ---- stage A tile, splitting to bf16 planes inline
    if (MODE == 1) {
        if (tid < 448) s_nb[tid] = nbr[m0 * 7 + tid];
        __syncthreads();
        size_t bbase = (size_t)bb * NP;
#pragma unroll 1
        for (int it = 0; it < 4; ++it) {
            int f = tid + it * 512;
            int r = f >> 5, c4 = (f & 31) * 4;
            size_t row = m0 + r;
            float4 z = *((const float4*)(Asrc + row * NC + c4));
            float4 acc = bf16x4_to_f32x4(*((const uint2*)(Y2in + row * NC + c4)));
#pragma unroll
            for (int t = 0; t < 7; ++t) {
                int j = s_nb[r * 7 + t];
                float4 v = bf16x4_to_f32x4(
                    *((const uint2*)(Y2in + (bbase + (size_t)j) * NC + c4)));
                acc.x += v.x; acc.y += v.y; acc.z += v.z; acc.w += v.w;
            }
            float4 a;
            a.x = OMA_F * (0.125f * acc.x) + z.x;
            a.y = OMA_F * (0.125f * acc.y) + z.y;
            a.z = OMA_F * (0.125f * acc.z) + z.z;
            a.w = OMA_F * (0.125f * acc.w) + z.w;
            unsigned h01, l01, h23, l23;
            split2(a.x, a.y, h01, l01);
            split2(a.z, a.w, h23, l23);
            *((uint2*)&AhT[r][c4]) = make_uint2(h01, h23);
            *((uint2*)&AlT[r][c4]) = make_uint2(l01, l23);
        }
    } else {
        // A[r][c] = points[b][c][n0+r]: float4 along n, split scalar, b16 writes
#pragma unroll
        for (int it = 0; it < 4; ++it) {
            int f = tid + it * 512;
            int c = f >> 4, rq = (f & 15) * 4;
            float4 v = *((const float4*)(Asrc + ((size_t)bb * NC + c) * NP + n0 + rq));
            float vv[4] = {v.x, v.y, v.z, v.w};
#pragma unroll
            for (int k = 0; k < 4; ++k) {
                unsigned short h, l;
                split1(vv[k], h, l);
                AhT[rq + k][c] = h;
                AlT[rq + k][c] = l;
            }
        }
    }
    __syncthreads();

    // ---- W frags AFTER staging (v11): no overlap with staging working set
    BU Bch[4], Bcl[4], Bgh[4], Bgl[4];
#pragma unroll
    for (int s = 0; s < 4; ++s) {
        int idx = ((s * 4 + quad) * 128 + ncol) * 2;
        Bch[s].u = WPc[idx];
        Bcl[s].u = WPc[idx + 1];
        Bgh[s].u = WPg[idx];
        Bgl[s].u = WPg[idx + 1];
    }

    ffrag accC[4], accG[4];
#pragma unroll
    for (int mt = 0; mt < 4; ++mt) { accC[mt] = (ffrag)0.0f; accG[mt] = (ffrag)0.0f; }

#pragma unroll
    for (int s = 0; s < 4; ++s) {
#pragma unroll
        for (int mt = 0; mt < 4; ++mt) {
            int m = mt * 16 + l15;
            int k = s * 32 + quad * 8;
            BU ah, al, rh, rl;
            ah.u = *((const uint4*)&AhT[m][k]);
            al.u = *((const uint4*)&AlT[m][k]);
#pragma unroll
            for (int w = 0; w < 4; ++w) {
                unsigned msk = ((ah.w[w] & 0x80008000u) >> 15) * 0xFFFFu;
                rh.w[w] = ah.w[w] & ~msk;
                rl.w[w] = al.w[w] & ~msk;
            }
            accC[mt] = __builtin_amdgcn_mfma_f32_16x16x32_bf16(rh.v, Bch[s].v, accC[mt], 0, 0, 0);
            accC[mt] = __builtin_amdgcn_mfma_f32_16x16x32_bf16(rh.v, Bcl[s].v, accC[mt], 0, 0, 0);
            accC[mt] = __builtin_amdgcn_mfma_f32_16x16x32_bf16(rl.v, Bch[s].v, accC[mt], 0, 0, 0);
            accG[mt] = __builtin_amdgcn_mfma_f32_16x16x32_bf16(ah.v, Bgh[s].v, accG[mt], 0, 0, 0);
            accG[mt] = __builtin_amdgcn_mfma_f32_16x16x32_bf16(ah.v, Bgl[s].v, accG[mt], 0, 0, 0);
            accG[mt] = __builtin_amdgcn_mfma_f32_16x16x32_bf16(al.v, Bgh[s].v, accG[mt], 0, 0, 0);
        }
    }

    // ---- epilogue: col = l15, row = 4*quad + r; residual p = hi + lo
#pragma unroll
    for (int mt = 0; mt < 4; ++mt) {
        int rbase = mt * 16 + quad * 4;
#pragma unroll
        for (int r = 0; r < 4; ++r) {
            int rr = rbase + r;
            unsigned hb = ((unsigned)AhT[rr][ncol]) << 16;
            unsigned lb = ((unsigned)AlT[rr][ncol]) << 16;
            float hp, lp;
            __builtin_memcpy(&hp, &hb, 4);
            __builtin_memcpy(&lp, &lb, 4);
            float p = hp + lp;
            size_t idx = (m0 + rr) * NC + ncol;
            Zout[idx] = p + ALPHA_F * accC[mt][r];
            Y2out[idx] = f32_to_bf16u(accG[mt][r]);
        }
    }
}

// ---------------------------------------------------------------------------
// agg2 (v11 structure, Y2 reads now bf16): agg + final_gemm + transpose.
// ---------------------------------------------------------------------------
__global__ __launch_bounds__(256) void agg2_kernel(const float* __restrict__ Z,
                                                   const unsigned short* __restrict__ Y2,
                                                   const int* __restrict__ nbr,
                                                   const float* __restrict__ Wuc,
                                                   const float* __restrict__ Wug,
                                                   float* __restrict__ U,
                                                   float* __restrict__ out2) {
    __shared__ float s1[6 * NC], s2[6 * NC];
    __shared__ float sm[8][132];
    int tid = threadIdx.x;
    int lane = tid & 31, rl = tid >> 5;
    for (int m = tid; m < 6 * NC; m += 256) { s1[m] = Wuc[m]; s2[m] = Wug[m]; }

    int xcd = blockIdx.x & 7;
    int slot = blockIdx.x >> 3;
    int bb = xcd * 2 + (slot >> 8);
    int rblk = slot & 255;
    int n0 = rblk * 8;
    size_t row = ((size_t)bb << 11) + n0 + rl;
    const int* nb = nbr + row * 7;
    size_t off = row * NC + lane * 4;
    float4 ys = bf16x4_to_f32x4(*((const uint2*)(Y2 + off)));
    size_t bbase = (size_t)bb * NP * NC;
#pragma unroll
    for (int t = 0; t < 7; ++t) {
        int j = nb[t];
        float4 v = bf16x4_to_f32x4(
            *((const uint2*)(Y2 + bbase + (size_t)j * NC + lane * 4)));
        ys.x += v.x; ys.y += v.y; ys.z += v.z; ys.w += v.w;
    }
    float4 z = *((const float4*)(Z + off));
    float4 o;
    o.x = OMA_F * (0.125f * ys.x) + z.x;
    o.y = OMA_F * (0.125f * ys.y) + z.y;
    o.z = OMA_F * (0.125f * ys.z) + z.z;
    o.w = OMA_F * (0.125f * ys.w) + z.w;

    __syncthreads();
    *((float4*)&sm[rl][lane * 4]) = o;

    float a1[6], a2[6];
#pragma unroll
    for (int oo = 0; oo < 6; ++oo) {
        float4 w1 = *((const float4*)&s1[oo * NC + lane * 4]);
        float4 w2 = *((const float4*)&s2[oo * NC + lane * 4]);
        a1[oo] = o.x * w1.x + o.y * w1.y + o.z * w1.z + o.w * w1.w;
        a2[oo] = o.x * w2.x + o.y * w2.y + o.z * w2.z + o.w * w2.w;
    }
#pragma unroll
    for (int s = 1; s < 32; s <<= 1) {
#pragma unroll
        for (int oo = 0; oo < 6; ++oo) {
            a1[oo] += __shfl_xor(a1[oo], s);
            a2[oo] += __shfl_xor(a2[oo], s);
        }
    }
    if (lane == 0) {
        float* Ur = U + row * 12;
        *((float4*)(Ur + 0)) = make_float4(a1[0], a1[1], a1[2], a1[3]);
        *((float4*)(Ur + 4)) = make_float4(a1[4], a1[5], a2[0], a2[1]);
        *((float4*)(Ur + 8)) = make_float4(a2[2], a2[3], a2[4], a2[5]);
    }

    __syncthreads();
    int c = tid >> 1, h = tid & 1;
    float4 v;
    v.x = sm[4 * h + 0][c];
    v.y = sm[4 * h + 1][c];
    v.z = sm[4 * h + 2][c];
    v.w = sm[4 * h + 3][c];
    *((float4*)(out2 + ((size_t)bb * NC + c) * NP + n0 + 4 * h)) = v;
}

// ---------------------------------------------------------------------------
// Final output: new_xyz (unchanged)
// ---------------------------------------------------------------------------
__global__ __launch_bounds__(256) void final_out_kernel(const float* __restrict__ U,
                                                        const int* __restrict__ nbr,
                                                        const float* __restrict__ xyz,
                                                        float* __restrict__ out) {
    size_t row = (size_t)blockIdx.x * 256 + threadIdx.x;
    int b = (int)(row >> 11), n = (int)(row & 2047);
    const int* nb = nbr + row * 7;
    float u1[6], u2[6];
#pragma unroll
    for (int o = 0; o < 6; ++o) { u1[o] = U[row * 12 + o]; u2[o] = U[row * 12 + 6 + o]; }
#pragma unroll
    for (int t = 0; t < 7; ++t) {
        int j = nb[t];
        const float* Uj = U + ((size_t)b * NP + j) * 12 + 6;
#pragma unroll
        for (int o = 0; o < 6; ++o) u2[o] += Uj[o];
    }
#pragma unroll
    for (int c = 0; c < 3; ++c)
#pragma unroll
        for (int s = 0; s < 2; ++s) {
            int o = c * 2 + s;
            float val = ALPHA_F * u1[o] + OMA_F * (0.125f * u2[o])
                      + xyz[(size_t)b * 3 * NP + (size_t)c * NP + n];
            out[(size_t)b * 3 * 2 * NP + (size_t)c * 2 * NP + (size_t)s * NP + n] = val;
        }
}

// ---------------------------------------------------------------------------
extern "C" void kernel_launch(void* const* d_in, const int* in_sizes, int n_in,
                              void* d_out, int out_size, void* d_ws, size_t ws_size,
                              hipStream_t stream) {
    const float* xyz    = (const float*)d_in[0];  // (16,3,2048)
    const float* points = (const float*)d_in[1];  // (16,128,2048)
    const float* Wc     = (const float*)d_in[2];  // (4,128,128)
    const float* Wg     = (const float*)d_in[3];  // (4,128,128)
    const float* Wuc    = (const float*)d_in[4];  // (6,128)
    const float* Wug    = (const float*)d_in[5];  // (6,128)
    float* out = (float*)d_out;

    char* ws = (char*)d_ws;
    size_t o = 0;
    int* nbr  = (int*)(ws + o);              o += (size_t)NB * NP * 7 * 4;
    uint4* WP = (uint4*)(ws + o);            o += (size_t)32768 * 16;      // 0.5 MB
    float* Za = (float*)(ws + o);            o += (size_t)NB * NP * NC * 4; // 16 MB
    float* Zb = (float*)(ws + o);            o += (size_t)NB * NP * NC * 4;
    unsigned short* Ya = (unsigned short*)(ws + o); o += (size_t)NB * NP * NC * 2; // 8 MB
    unsigned short* Yb = (unsigned short*)(ws + o); o += (size_t)NB * NP * NC * 2;
    float* U  = (float*)(ws + o);            o += (size_t)NB * NP * 12 * 4;

    const int GEMM_GRID = NB * NP / 64;   // 512 tiles
    #define WPC(L) (WP + (size_t)((L) * 2 + 0) * 4096)
    #define WPG(L) (WP + (size_t)((L) * 2 + 1) * 4096)

    // 0) pre-split weights (one-time)
    prep_w_kernel<<<64, 256, 0, stream>>>(Wc, Wg, WP);
    // 1) KNN
    knn_kernel<<<dim3(NP / 64, NB), 256, 0, stream>>>(xyz, nbr);
    // 2) GCN blocks — agg fused into next block's A-staging; Y2 in bf16
    gemm_fused_kernel<0><<<GEMM_GRID, 512, 0, stream>>>(points, nullptr, nullptr,
        WPC(0), WPG(0), Za, Ya);
    gemm_fused_kernel<1><<<GEMM_GRID, 512, 0, stream>>>(Za, Ya, nbr,
        WPC(1), WPG(1), Zb, Yb);
    gemm_fused_kernel<1><<<GEMM_GRID, 512, 0, stream>>>(Zb, Yb, nbr,
        WPC(2), WPG(2), Za, Ya);
    gemm_fused_kernel<1><<<GEMM_GRID, 512, 0, stream>>>(Za, Ya, nbr,
        WPC(3), WPG(3), Zb, Yb);
    // 3) fused tail: last agg + final small GEMMs + transpose
    float* out2 = out + (size_t)NB * 3 * 2 * NP;
    agg2_kernel<<<dim3(NB * NP / 8), 256, 0, stream>>>(Zb, Yb, nbr, Wuc, Wug, U, out2);
    // 4) new_xyz
    final_out_kernel<<<dim3(NB * NP / 256), 256, 0, stream>>>(U, nbr, xyz, out);
}

// Round 17
// 187.142 us; speedup vs baseline: 2.7387x; 1.0206x over previous
//
#include <hip/hip_runtime.h>
#include <hip/hip_bf16.h>

// Problem constants
static constexpr int NB = 16;     // batches
static constexpr int NP = 2048;   // points per batch
static constexpr int NC = 128;    // channels
#define ALPHA_F ((float)(8.0/9.0))
#define OMA_F   ((float)(1.0 - 8.0/9.0))

typedef __attribute__((ext_vector_type(8))) short bfrag;   // 8 bf16 (4 VGPR)
typedef __attribute__((ext_vector_type(4))) float ffrag;   // 4 fp32 acc

union BU { bfrag v; uint4 u; unsigned int w[4]; };

__device__ inline void split2(float x, float y, unsigned& hi, unsigned& lo) {
    __hip_bfloat162 h = __float22bfloat162_rn(make_float2(x, y));
    float2 hb = __bfloat1622float2(h);
    __hip_bfloat162 l = __float22bfloat162_rn(make_float2(x - hb.x, y - hb.y));
    __builtin_memcpy(&hi, &h, 4);
    __builtin_memcpy(&lo, &l, 4);
}

__device__ inline void split1(float x, unsigned short& h, unsigned short& l) {
    __hip_bfloat16 hb = __float2bfloat16(x);
    float hf = __bfloat162float(hb);
    __hip_bfloat16 lb = __float2bfloat16(x - hf);
    __builtin_memcpy(&h, &hb, 2);
    __builtin_memcpy(&l, &lb, 2);
}

// unpack 4 packed bf16 (uint2) -> float4
__device__ inline float4 bf16x4_to_f32x4(uint2 u) {
    unsigned w0 = (u.x & 0xFFFFu) << 16, w1 = u.x & 0xFFFF0000u;
    unsigned w2 = (u.y & 0xFFFFu) << 16, w3 = u.y & 0xFFFF0000u;
    float4 r;
    __builtin_memcpy(&r.x, &w0, 4);
    __builtin_memcpy(&r.y, &w1, 4);
    __builtin_memcpy(&r.z, &w2, 4);
    __builtin_memcpy(&r.w, &w3, 4);
    return r;
}

// pack float -> bf16 ushort (RNE)
__device__ inline unsigned short f32_to_bf16u(float x) {
    __hip_bfloat16 h = __float2bfloat16(x);
    unsigned short u;
    __builtin_memcpy(&u, &h, 2);
    return u;
}

// pack float4 -> 4 bf16 in uint2 (RNE)
__device__ inline uint2 f32x4_to_bf16x4(float4 v) {
    __hip_bfloat162 h01 = __float22bfloat162_rn(make_float2(v.x, v.y));
    __hip_bfloat162 h23 = __float22bfloat162_rn(make_float2(v.z, v.w));
    uint2 r;
    __builtin_memcpy(&r.x, &h01, 4);
    __builtin_memcpy(&r.y, &h23, 4);
    return r;
}

// ---------------------------------------------------------------------------
// KNN v7.1 (measured best, ~35us; unchanged).
// ---------------------------------------------------------------------------
__global__ __launch_bounds__(256) void knn_kernel(const float* __restrict__ xyz,
                                                  int* __restrict__ nbr) {
    __shared__ float4 sp[NP];            // 32 KB (XOR-swizzled slots)
    __shared__ float  md[64][33];
    __shared__ int    mi[64][33];
    int b = blockIdx.y;
    const float* X = xyz + (size_t)b * 3 * NP;
    for (int m = threadIdx.x; m < NP; m += 256) {
        float x = X[m], y = X[NP + m], z = X[2 * NP + m];
        sp[m ^ ((m >> 5) & 7)] = make_float4(x, y, z, x * x + y * y + z * z);
    }
    __syncthreads();

    int tid = threadIdx.x;
    int p = tid >> 2;
    int q = tid & 3;
    int base = blockIdx.x * 64;
    int n = base + p;
    float4 me = sp[n ^ ((n >> 5) & 7)];
    float xi = me.x, yi = me.y, zi = me.z, qi = me.w;

    // ---- pass 1: true group-min for the 16 owned groups (g = q*16 + gg)
    unsigned gd[8];
#pragma unroll
    for (int t = 0; t < 8; ++t) gd[t] = 0x7F7FFFFFu;
#pragma unroll 1
    for (int gg = 0; gg < 16; ++gg) {
        int g = q * 16 + gg;
        const float4* gp = sp + g * 32;
        float m0 = 3.4e38f, m1 = m0, m2 = m0, m3 = m0;
#pragma unroll
        for (int k = 0; k < 32; k += 4) {
            float4 a0 = gp[(k + 0) ^ q];
            float4 a1 = gp[(k + 1) ^ q];
            float4 a2 = gp[(k + 2) ^ q];
            float4 a3 = gp[(k + 3) ^ q];
            m0 = fminf(m0, qi + a0.w - 2.0f * (xi * a0.x + yi * a0.y + zi * a0.z));
            m1 = fminf(m1, qi + a1.w - 2.0f * (xi * a1.x + yi * a1.y + zi * a1.z));
            m2 = fminf(m2, qi + a2.w - 2.0f * (xi * a2.x + yi * a2.y + zi * a2.z));
            m3 = fminf(m3, qi + a3.w - 2.0f * (xi * a3.x + yi * a3.y + zi * a3.z));
        }
        float gm = fmaxf(fminf(fminf(m0, m1), fminf(m2, m3)), 0.0f);
        unsigned pg; __builtin_memcpy(&pg, &gm, 4);
        pg = (pg & ~63u) | (unsigned)g;
        // sorted-insert via min/max identity (keys unique -> exact)
        unsigned prev = gd[0];
        gd[0] = gd[0] < pg ? gd[0] : pg;
#pragma unroll
        for (int t = 1; t < 8; ++t) {
            unsigned mx = prev > pg ? prev : pg;
            prev = gd[t];
            gd[t] = gd[t] < mx ? gd[t] : mx;
        }
    }

    // ---- cross-lane merge: top-8 of the 4 lanes' sorted lists (bitonic)
#define CEU(A, B) { unsigned _lo = (A) < (B) ? (A) : (B); \
                    unsigned _hi = (A) < (B) ? (B) : (A); (A) = _lo; (B) = _hi; }
    unsigned cA[8];
#pragma unroll
    for (int i = 0; i < 8; ++i) {
        unsigned pb = (unsigned)__shfl_xor((int)gd[7 - i], 1);
        cA[i] = gd[i] < pb ? gd[i] : pb;
    }
    CEU(cA[0], cA[4]); CEU(cA[1], cA[5]); CEU(cA[2], cA[6]); CEU(cA[3], cA[7]);
    CEU(cA[0], cA[2]); CEU(cA[1], cA[3]); CEU(cA[4], cA[6]); CEU(cA[5], cA[7]);
    CEU(cA[0], cA[1]); CEU(cA[2], cA[3]); CEU(cA[4], cA[5]); CEU(cA[6], cA[7]);
    unsigned dA[8];
#pragma unroll
    for (int i = 0; i < 8; ++i) {
        unsigned pb = (unsigned)__shfl_xor((int)cA[7 - i], 2);
        dA[i] = cA[i] < pb ? cA[i] : pb;
    }
    unsigned long long mask = 0ull;
#pragma unroll
    for (int i = 0; i < 8; ++i) mask |= (1ull << (dA[i] & 63u));

    // ---- pass 2: full insert over winning groups, ascending group order
    float bd[8]; int bi[8];
#pragma unroll
    for (int t = 0; t < 8; ++t) { bd[t] = 3.4e38f; bi[t] = 0; }
    while (mask) {
        int g = (int)__builtin_ctzll(mask);
        mask &= (mask - 1ull);
        int sw = g & 7;
        int jb = g * 32 + q;
#pragma unroll
        for (int i = 0; i < 8; ++i) {
            int j0 = jb + i * 4;
            float4 c4v = sp[j0 ^ sw];
            float inner = xi * c4v.x + yi * c4v.y + zi * c4v.z;
            float d = qi + c4v.w - 2.0f * inner;
            bool c[8];
#pragma unroll
            for (int t = 0; t < 8; ++t) c[t] = d < bd[t];
#pragma unroll
            for (int t = 7; t >= 1; --t) {
                bd[t] = c[t - 1] ? bd[t - 1] : (c[t] ? d : bd[t]);
                bi[t] = c[t - 1] ? bi[t - 1] : (c[t] ? j0 : bi[t]);
            }
            bd[0] = c[0] ? d : bd[0];
            bi[0] = c[0] ? j0 : bi[0];
        }
    }
#pragma unroll
    for (int t = 0; t < 8; ++t) {
        md[p][q * 8 + t] = bd[t];
        mi[p][q * 8 + t] = bi[t];
    }
    __syncthreads();

    if (tid < 64) {
        float fd[8]; int fi[8];
#pragma unroll
        for (int t = 0; t < 8; ++t) { fd[t] = 3.4e38f; fi[t] = 0; }
#pragma unroll 4
        for (int cc = 0; cc < 32; ++cc) {
            float d = md[tid][cc];
            int j = mi[tid][cc];
            bool c[8];
#pragma unroll
            for (int t = 0; t < 8; ++t) c[t] = d < fd[t];
#pragma unroll
            for (int t = 7; t >= 1; --t) {
                fd[t] = c[t - 1] ? fd[t - 1] : (c[t] ? d : fd[t]);
                fi[t] = c[t - 1] ? fi[t - 1] : (c[t] ? j : fi[t]);
            }
            fd[0] = c[0] ? d : fd[0];
            fi[0] = c[0] ? j : fi[0];
        }
        int row = b * NP + base + tid;
#pragma unroll
        for (int t = 0; t < 7; ++t) nbr[row * 7 + t] = fi[t + 1];
    }
}

// ---------------------------------------------------------------------------
// Pre-split W into MFMA-frag-ordered bf16 hi/lo uint4 pairs (one-time).
// ---------------------------------------------------------------------------
__global__ __launch_bounds__(256) void prep_w_kernel(const float* __restrict__ Wc,
                                                     const float* __restrict__ Wg,
                                                     uint4* __restrict__ WP) {
    int t = blockIdx.x * 256 + threadIdx.x;
    int ncol = t & 127;
    int quad = (t >> 7) & 3;
    int s = (t >> 9) & 3;
    int mat = (t >> 11) & 1;
    int layer = t >> 12;
    const float* W = (mat ? Wg : Wc) + (size_t)layer * NC * NC + (size_t)ncol * NC + s * 32 + quad * 8;
    float4 a = *((const float4*)W);
    float4 b = *((const float4*)(W + 4));
    BU hi, lo;
    split2(a.x, a.y, hi.w[0], lo.w[0]);
    split2(a.z, a.w, hi.w[1], lo.w[1]);
    split2(b.x, b.y, hi.w[2], lo.w[2]);
    split2(b.z, b.w, hi.w[3], lo.w[3]);
    WP[t * 2] = hi.u;
    WP[t * 2 + 1] = lo.u;
}

// ---------------------------------------------------------------------------
// Fused GCN block v8 (round-17): v16 + bf16 Z storage.
// Round-16 validated the bytes-at-the-boundary lever (bf16 Y2: -6.3us).
// Z is the remaining fp32 inter-layer tensor (~128 MB total traffic).
// Store Z as single bf16: saves ~64 MB. Precision: Z's downstream consumer
// already reconstructs A at bf16-pair precision (hi/lo split right after the
// z-add); only the final P5 output sees the single-bf16 error (~|Z|*2^-9 per
// store, 4 stores) -> predicted absmax <= ~0.15 vs threshold 0.22.
// MODE 0 takes fp32 points via Psrc; MODE 1 takes bf16 Z via Zin.
// ---------------------------------------------------------------------------
template <int MODE>
__global__ __launch_bounds__(512, 4) void gemm_fused_kernel(const float* __restrict__ Psrc,
                                                            const unsigned short* __restrict__ Zin,
                                                            const unsigned short* __restrict__ Y2in,
                                                            const int* __restrict__ nbr,
                                                            const uint4* __restrict__ WPc,
                                                            const uint4* __restrict__ WPg,
                                                            unsigned short* __restrict__ Zout,
                                                            unsigned short* __restrict__ Y2out) {
    __shared__ unsigned short AhT[64][136];   // 17.4 KB
    __shared__ unsigned short AlT[64][136];   // 17.4 KB
    __shared__ int s_nb[448];
    int tid = threadIdx.x;
    int wid = tid >> 6, lane = tid & 63;
    int quad = lane >> 4, l15 = lane & 15;
    int xcd = blockIdx.x & 7;
    int slot = blockIdx.x >> 3;
    int bb = xcd * 2 + (slot >> 5);           // batch
    int n0 = (slot & 31) << 6;                // tile base within batch
    size_t m0 = (size_t)bb * NP + n0;
    int ncol = wid * 16 + l15;

    // ---- stage A tile, splitting to bf16 planes inline
    if (MODE == 1) {
        if (tid < 448) s_nb[tid] = nbr[m0 * 7 + tid];
        __syncthreads();
        size_t bbase = (size_t)bb * NP;
#pragma unroll 1
        for (int it = 0; it < 4; ++it) {
            int f = tid + it * 512;
            int r = f >> 5, c4 = (f & 31) * 4;
            size_t row = m0 + r;
            float4 z = bf16x4_to_f32x4(*((const uint2*)(Zin + row * NC + c4)));
            float4 acc = bf16x4_to_f32x4(*((const uint2*)(Y2in + row * NC + c4)));
#pragma unroll
            for (int t = 0; t < 7; ++t) {
                int j = s_nb[r * 7 + t];
                float4 v = bf16x4_to_f32x4(
                    *((const uint2*)(Y2in + (bbase + (size_t)j) * NC + c4)));
                acc.x += v.x; acc.y += v.y; acc.z += v.z; acc.w += v.w;
            }
            float4 a;
            a.x = OMA_F * (0.125f * acc.x) + z.x;
            a.y = OMA_F * (0.125f * acc.y) + z.y;
            a.z = OMA_F * (0.125f * acc.z) + z.z;
            a.w = OMA_F * (0.125f * acc.w) + z.w;
            unsigned h01, l01, h23, l23;
            split2(a.x, a.y, h01, l01);
            split2(a.z, a.w, h23, l23);
            *((uint2*)&AhT[r][c4]) = make_uint2(h01, h23);
            *((uint2*)&AlT[r][c4]) = make_uint2(l01, l23);
        }
    } else {
        // A[r][c] = points[b][c][n0+r]: float4 along n, split scalar, b16 writes
#pragma unroll
        for (int it = 0; it < 4; ++it) {
            int f = tid + it * 512;
            int c = f >> 4, rq = (f & 15) * 4;
            float4 v = *((const float4*)(Psrc + ((size_t)bb * NC + c) * NP + n0 + rq));
            float vv[4] = {v.x, v.y, v.z, v.w};
#pragma unroll
            for (int k = 0; k < 4; ++k) {
                unsigned short h, l;
                split1(vv[k], h, l);
                AhT[rq + k][c] = h;
                AlT[rq + k][c] = l;
            }
        }
    }
    __syncthreads();

    // ---- W frags AFTER staging (v11): no overlap with staging working set
    BU Bch[4], Bcl[4], Bgh[4], Bgl[4];
#pragma unroll
    for (int s = 0; s < 4; ++s) {
        int idx = ((s * 4 + quad) * 128 + ncol) * 2;
        Bch[s].u = WPc[idx];
        Bcl[s].u = WPc[idx + 1];
        Bgh[s].u = WPg[idx];
        Bgl[s].u = WPg[idx + 1];
    }

    ffrag accC[4], accG[4];
#pragma unroll
    for (int mt = 0; mt < 4; ++mt) { accC[mt] = (ffrag)0.0f; accG[mt] = (ffrag)0.0f; }

#pragma unroll
    for (int s = 0; s < 4; ++s) {
#pragma unroll
        for (int mt = 0; mt < 4; ++mt) {
            int m = mt * 16 + l15;
            int k = s * 32 + quad * 8;
            BU ah, al, rh, rl;
            ah.u = *((const uint4*)&AhT[m][k]);
            al.u = *((const uint4*)&AlT[m][k]);
#pragma unroll
            for (int w = 0; w < 4; ++w) {
                unsigned msk = ((ah.w[w] & 0x80008000u) >> 15) * 0xFFFFu;
                rh.w[w] = ah.w[w] & ~msk;
                rl.w[w] = al.w[w] & ~msk;
            }
            accC[mt] = __builtin_amdgcn_mfma_f32_16x16x32_bf16(rh.v, Bch[s].v, accC[mt], 0, 0, 0);
            accC[mt] = __builtin_amdgcn_mfma_f32_16x16x32_bf16(rh.v, Bcl[s].v, accC[mt], 0, 0, 0);
            accC[mt] = __builtin_amdgcn_mfma_f32_16x16x32_bf16(rl.v, Bch[s].v, accC[mt], 0, 0, 0);
            accG[mt] = __builtin_amdgcn_mfma_f32_16x16x32_bf16(ah.v, Bgh[s].v, accG[mt], 0, 0, 0);
            accG[mt] = __builtin_amdgcn_mfma_f32_16x16x32_bf16(ah.v, Bgl[s].v, accG[mt], 0, 0, 0);
            accG[mt] = __builtin_amdgcn_mfma_f32_16x16x32_bf16(al.v, Bgh[s].v, accG[mt], 0, 0, 0);
        }
    }

    // ---- epilogue: col = l15, row = 4*quad + r; residual p = hi + lo
#pragma unroll
    for (int mt = 0; mt < 4; ++mt) {
        int rbase = mt * 16 + quad * 4;
#pragma unroll
        for (int r = 0; r < 4; ++r) {
            int rr = rbase + r;
            unsigned hb = ((unsigned)AhT[rr][ncol]) << 16;
            unsigned lb = ((unsigned)AlT[rr][ncol]) << 16;
            float hp, lp;
            __builtin_memcpy(&hp, &hb, 4);
            __builtin_memcpy(&lp, &lb, 4);
            float p = hp + lp;
            size_t idx = (m0 + rr) * NC + ncol;
            Zout[idx] = f32_to_bf16u(p + ALPHA_F * accC[mt][r]);
            Y2out[idx] = f32_to_bf16u(accG[mt][r]);
        }
    }
}

// ---------------------------------------------------------------------------
// agg2 (v16 structure, Z reads now bf16): agg + final_gemm + transpose.
// ---------------------------------------------------------------------------
__global__ __launch_bounds__(256) void agg2_kernel(const unsigned short* __restrict__ Z,
                                                   const unsigned short* __restrict__ Y2,
                                                   const int* __restrict__ nbr,
                                                   const float* __restrict__ Wuc,
                                                   const float* __restrict__ Wug,
                                                   float* __restrict__ U,
                                                   float* __restrict__ out2) {
    __shared__ float s1[6 * NC], s2[6 * NC];
    __shared__ float sm[8][132];
    int tid = threadIdx.x;
    int lane = tid & 31, rl = tid >> 5;
    for (int m = tid; m < 6 * NC; m += 256) { s1[m] = Wuc[m]; s2[m] = Wug[m]; }

    int xcd = blockIdx.x & 7;
    int slot = blockIdx.x >> 3;
    int bb = xcd * 2 + (slot >> 8);
    int rblk = slot & 255;
    int n0 = rblk * 8;
    size_t row = ((size_t)bb << 11) + n0 + rl;
    const int* nb = nbr + row * 7;
    size_t off = row * NC + lane * 4;
    float4 ys = bf16x4_to_f32x4(*((const uint2*)(Y2 + off)));
    size_t bbase = (size_t)bb * NP * NC;
#pragma unroll
    for (int t = 0; t < 7; ++t) {
        int j = nb[t];
        float4 v = bf16x4_to_f32x4(
            *((const uint2*)(Y2 + bbase + (size_t)j * NC + lane * 4)));
        ys.x += v.x; ys.y += v.y; ys.z += v.z; ys.w += v.w;
    }
    float4 z = bf16x4_to_f32x4(*((const uint2*)(Z + off)));
    float4 o;
    o.x = OMA_F * (0.125f * ys.x) + z.x;
    o.y = OMA_F * (0.125f * ys.y) + z.y;
    o.z = OMA_F * (0.125f * ys.z) + z.z;
    o.w = OMA_F * (0.125f * ys.w) + z.w;

    __syncthreads();
    *((float4*)&sm[rl][lane * 4]) = o;

    float a1[6], a2[6];
#pragma unroll
    for (int oo = 0; oo < 6; ++oo) {
        float4 w1 = *((const float4*)&s1[oo * NC + lane * 4]);
        float4 w2 = *((const float4*)&s2[oo * NC + lane * 4]);
        a1[oo] = o.x * w1.x + o.y * w1.y + o.z * w1.z + o.w * w1.w;
        a2[oo] = o.x * w2.x + o.y * w2.y + o.z * w2.z + o.w * w2.w;
    }
#pragma unroll
    for (int s = 1; s < 32; s <<= 1) {
#pragma unroll
        for (int oo = 0; oo < 6; ++oo) {
            a1[oo] += __shfl_xor(a1[oo], s);
            a2[oo] += __shfl_xor(a2[oo], s);
        }
    }
    if (lane == 0) {
        float* Ur = U + row * 12;
        *((float4*)(Ur + 0)) = make_float4(a1[0], a1[1], a1[2], a1[3]);
        *((float4*)(Ur + 4)) = make_float4(a1[4], a1[5], a2[0], a2[1]);
        *((float4*)(Ur + 8)) = make_float4(a2[2], a2[3], a2[4], a2[5]);
    }

    __syncthreads();
    int c = tid >> 1, h = tid & 1;
    float4 v;
    v.x = sm[4 * h + 0][c];
    v.y = sm[4 * h + 1][c];
    v.z = sm[4 * h + 2][c];
    v.w = sm[4 * h + 3][c];
    *((float4*)(out2 + ((size_t)bb * NC + c) * NP + n0 + 4 * h)) = v;
}

// ---------------------------------------------------------------------------
// Final output: new_xyz (unchanged)
// ---------------------------------------------------------------------------
__global__ __launch_bounds__(256) void final_out_kernel(const float* __restrict__ U,
                                                        const int* __restrict__ nbr,
                                                        const float* __restrict__ xyz,
                                                        float* __restrict__ out) {
    size_t row = (size_t)blockIdx.x * 256 + threadIdx.x;
    int b = (int)(row >> 11), n = (int)(row & 2047);
    const int* nb = nbr + row * 7;
    float u1[6], u2[6];
#pragma unroll
    for (int o = 0; o < 6; ++o) { u1[o] = U[row * 12 + o]; u2[o] = U[row * 12 + 6 + o]; }
#pragma unroll
    for (int t = 0; t < 7; ++t) {
        int j = nb[t];
        const float* Uj = U + ((size_t)b * NP + j) * 12 + 6;
#pragma unroll
        for (int o = 0; o < 6; ++o) u2[o] += Uj[o];
    }
#pragma unroll
    for (int c = 0; c < 3; ++c)
#pragma unroll
        for (int s = 0; s < 2; ++s) {
            int o = c * 2 + s;
            float val = ALPHA_F * u1[o] + OMA_F * (0.125f * u2[o])
                      + xyz[(size_t)b * 3 * NP + (size_t)c * NP + n];
            out[(size_t)b * 3 * 2 * NP + (size_t)c * 2 * NP + (size_t)s * NP + n] = val;
        }
}

// ---------------------------------------------------------------------------
extern "C" void kernel_launch(void* const* d_in, const int* in_sizes, int n_in,
                              void* d_out, int out_size, void* d_ws, size_t ws_size,
                              hipStream_t stream) {
    const float* xyz    = (const float*)d_in[0];  // (16,3,2048)
    const float* points = (const float*)d_in[1];  // (16,128,2048)
    const float* Wc     = (const float*)d_in[2];  // (4,128,128)
    const float* Wg     = (const float*)d_in[3];  // (4,128,128)
    const float* Wuc    = (const float*)d_in[4];  // (6,128)
    const float* Wug    = (const float*)d_in[5];  // (6,128)
    float* out = (float*)d_out;

    char* ws = (char*)d_ws;
    size_t o = 0;
    int* nbr  = (int*)(ws + o);              o += (size_t)NB * NP * 7 * 4;
    uint4* WP = (uint4*)(ws + o);            o += (size_t)32768 * 16;      // 0.5 MB
    unsigned short* Za = (unsigned short*)(ws + o); o += (size_t)NB * NP * NC * 2; // 8 MB
    unsigned short* Zb = (unsigned short*)(ws + o); o += (size_t)NB * NP * NC * 2;
    unsigned short* Ya = (unsigned short*)(ws + o); o += (size_t)NB * NP * NC * 2;
    unsigned short* Yb = (unsigned short*)(ws + o); o += (size_t)NB * NP * NC * 2;
    float* U  = (float*)(ws + o);            o += (size_t)NB * NP * 12 * 4;

    const int GEMM_GRID = NB * NP / 64;   // 512 tiles
    #define WPC(L) (WP + (size_t)((L) * 2 + 0) * 4096)
    #define WPG(L) (WP + (size_t)((L) * 2 + 1) * 4096)

    // 0) pre-split weights (one-time)
    prep_w_kernel<<<64, 256, 0, stream>>>(Wc, Wg, WP);
    // 1) KNN
    knn_kernel<<<dim3(NP / 64, NB), 256, 0, stream>>>(xyz, nbr);
    // 2) GCN blocks — agg fused into next block's A-staging; Z and Y2 in bf16
    gemm_fused_kernel<0><<<GEMM_GRID, 512, 0, stream>>>(points, nullptr, nullptr, nullptr,
        WPC(0), WPG(0), Za, Ya);
    gemm_fused_kernel<1><<<GEMM_GRID, 512, 0, stream>>>(nullptr, Za, Ya, nbr,
        WPC(1), WPG(1), Zb, Yb);
    gemm_fused_kernel<1><<<GEMM_GRID, 512, 0, stream>>>(nullptr, Zb, Yb, nbr,
        WPC(2), WPG(2), Za, Ya);
    gemm_fused_kernel<1><<<GEMM_GRID, 512, 0, stream>>>(nullptr, Za, Ya, nbr,
        WPC(3), WPG(3), Zb, Yb);
    // 3) fused tail: last agg + final small GEMMs + transpose
    float* out2 = out + (size_t)NB * 3 * 2 * NP;
    agg2_kernel<<<dim3(NB * NP / 8), 256, 0, stream>>>(Zb, Yb, nbr, Wuc, Wug, U, out2);
    // 4) new_xyz
    final_out_kernel<<<dim3(NB * NP / 256), 256, 0, stream>>>(U, nbr, xyz, out);
}